// Round 1
// baseline (519.446 us; speedup 1.0000x reference)
//
#include <hip/hip_runtime.h>
#include <hip/hip_bf16.h>
#include <math.h>

// COSGATEncoder: N=50000, E=1280000, D=64, HEADS=1. f32 in/out (runtime-detected,
// bf16 fallback), edge_index int64 (runtime-detected, int32 fallback).
// R13: k_edge restructured for memory-level parallelism. Stage 0 batches csr
// loads to regs; stage 1 batch-issues ALL gathers (fhat fp8 + Hmat bf16 + a_r)
// in one latency exposure; Hmat rows stay in registers (uint4 hm[8]) across the
// softmax so phase 3 is pure VALU (no second gather pass / no sg round-trip).
// Scalarized s/deg via readfirstlane. Overflow deg>CAP keeps old global path.
// Rest = R12 (fp8 fhat rows, packed 4B csr entries, fused prep/epilogues).

constexpr int D = 64;
constexpr int CAP = 64;
constexpr float NEG_SLOPE = 0.2f;
constexpr float EPS_COS = 1e-8f;
constexpr float EPS_SM = 1e-16f;

#if defined(__has_builtin)
#if __has_builtin(__builtin_amdgcn_cvt_pk_f32_fp8) && __has_builtin(__builtin_amdgcn_cvt_pk_fp8_f32)
#define HW_FP8 1
#endif
#endif

typedef float floatx2 __attribute__((ext_vector_type(2)));

__device__ __forceinline__ float wred_sum(float v) {
#pragma unroll
  for (int off = 32; off > 0; off >>= 1) v += __shfl_xor(v, off, 64);
  return v;
}
__device__ __forceinline__ float elu1(float x) { return x > 0.f ? x : __expf(x) - 1.f; }
__device__ __forceinline__ float sane(float v) {
  return (v == v && fabsf(v) < 1e30f) ? v : 0.f;
}
__device__ __forceinline__ float ldv(const void* p, size_t i, int f32) {
  return f32 ? ((const float*)p)[i]
             : __bfloat162float(((const __hip_bfloat16*)p)[i]);
}
__device__ __forceinline__ void stv(void* p, size_t i, int f32, float v) {
  if (f32) ((float*)p)[i] = v;
  else ((__hip_bfloat16*)p)[i] = __float2bfloat16(v);
}
__device__ __forceinline__ float b2f(unsigned short u) {
  return __uint_as_float(((unsigned int)u) << 16);
}
__device__ __forceinline__ void unp8(uint4 u, float* f) {
  f[0] = __uint_as_float(u.x << 16);
  f[1] = __uint_as_float(u.x & 0xffff0000u);
  f[2] = __uint_as_float(u.y << 16);
  f[3] = __uint_as_float(u.y & 0xffff0000u);
  f[4] = __uint_as_float(u.z << 16);
  f[5] = __uint_as_float(u.z & 0xffff0000u);
  f[6] = __uint_as_float(u.w << 16);
  f[7] = __uint_as_float(u.w & 0xffff0000u);
}

// ---- fp8 helpers: HW e4m3 when available, f16-msb (e5m2-like) fallback ----
__device__ __forceinline__ unsigned char enc_fp8(float v) {
#ifdef HW_FP8
  int pk = __builtin_amdgcn_cvt_pk_fp8_f32(v, v, 0, false);
  return (unsigned char)(pk & 0xFF);
#else
  _Float16 h = (_Float16)v;
  unsigned short ub;
  __builtin_memcpy(&ub, &h, 2);
  return (unsigned char)((ub + 0x80) >> 8);  // RNE-ish truncate to top byte
#endif
}
__device__ __forceinline__ void dec_fp8x8(uint2 u, float* f) {
#ifdef HW_FP8
  floatx2 a = __builtin_amdgcn_cvt_pk_f32_fp8(u.x, false);
  floatx2 b = __builtin_amdgcn_cvt_pk_f32_fp8(u.x, true);
  floatx2 c = __builtin_amdgcn_cvt_pk_f32_fp8(u.y, false);
  floatx2 d = __builtin_amdgcn_cvt_pk_f32_fp8(u.y, true);
  f[0] = a[0]; f[1] = a[1]; f[2] = b[0]; f[3] = b[1];
  f[4] = c[0]; f[5] = c[1]; f[6] = d[0]; f[7] = d[1];
#else
#pragma unroll
  for (int i = 0; i < 8; ++i) {
    unsigned int byte = (i < 4 ? (u.x >> (8 * i)) : (u.y >> (8 * (i - 4)))) & 0xFF;
    unsigned short hb = (unsigned short)(byte << 8);
    _Float16 h;
    __builtin_memcpy(&h, &hb, 2);
    f[i] = (float)h;
  }
#endif
}

// packed csr entry: bits 0..17 = src, bits 18..31 = gate quantized to 14 bits
__device__ __forceinline__ unsigned int pack_sg(int src, float g) {
  int gq = (int)(g * 16383.f + 0.5f);
  return ((unsigned int)src & 0x3FFFFu) | ((unsigned int)gq << 18);
}
__device__ __forceinline__ int upk_src(unsigned int e, int N) {
  return min((int)(e & 0x3FFFFu), N - 1);
}
__device__ __forceinline__ float upk_gate(unsigned int e) {
  return (float)(e >> 18) * (1.f / 16383.f);
}

// shared prep body: node features (lane=feature) -> fhat(fp8), Hmat(bf16), a_l, a_r
__device__ __forceinline__ void prep_node(float f, int f32, int wid, int lane,
                                          const void* __restrict__ W,
                                          const void* __restrict__ att,
                                          unsigned char* __restrict__ fhat,
                                          __hip_bfloat16* __restrict__ Hmat,
                                          float* __restrict__ a_l,
                                          float* __restrict__ a_r) {
  float n2 = wred_sum(f * f);
  float nrm = fmaxf(sqrtf(n2), EPS_COS);
  fhat[(size_t)wid * D + lane] = enc_fp8(f / nrm);
  float Hc = 0.f;
  if (f32) {
    const float* Wf = (const float*)W;
#pragma unroll 8
    for (int k = 0; k < D; ++k) Hc += __shfl(f, k, 64) * Wf[k * D + lane];
  } else {
    const __hip_bfloat16* Wb = (const __hip_bfloat16*)W;
#pragma unroll 8
    for (int k = 0; k < D; ++k) Hc += __shfl(f, k, 64) * __bfloat162float(Wb[k * D + lane]);
  }
  Hmat[(size_t)wid * D + lane] = __float2bfloat16(Hc);
  float al = wred_sum(Hc * ldv(att, lane, f32));
  float ar = wred_sum(Hc * ldv(att, D + lane, f32));
  if (lane == 0) {
    a_l[wid] = al;
    a_r[wid] = ar;
  }
}

// fused: per-block dtype detect + degree count + layer-0 prep
__global__ void __launch_bounds__(256) k_init(const unsigned short* __restrict__ xu,
                                              const int* __restrict__ ei,
                                              int* __restrict__ flags,
                                              int* __restrict__ counts,
                                              const void* __restrict__ x,
                                              const void* __restrict__ W,
                                              const void* __restrict__ att,
                                              unsigned char* __restrict__ fhat,
                                              __hip_bfloat16* __restrict__ Hmat,
                                              float* __restrict__ a_l,
                                              float* __restrict__ a_r, int N, int E) {
  __shared__ int sf[2];
  const int tid = threadIdx.x;
  if (tid < 64) {
    float v = b2f(xu[tid]);
    float a = fabsf(v);
    unsigned long long m = __ballot(a > 1e-4f && a < 100.f);
    unsigned long long m2 = __ballot(ei[2 * tid + 1] != 0);
    if (tid == 0) {
      sf[0] = (__popcll(m) >= 60) ? 0 : 1;  // 1 => f32
      sf[1] = (m2 == 0ull) ? 1 : 0;         // 1 => int64
      if (blockIdx.x == 0) {
        flags[0] = sf[0];
        flags[1] = sf[1];
      }
    }
  }
  __syncthreads();
  const int f32 = sf[0], wide = sf[1];
  {
    const int e0 = (blockIdx.x * 256 + tid) * 2;
    if (e0 < E) {
      int d0, d1;
      const bool has1 = (e0 + 1 < E);
      if (wide) {
        int4 v = *(const int4*)(ei + 2 * (size_t)E + 2 * (size_t)e0);
        d0 = v.x;
        d1 = v.z;
      } else {
        int2 v = *(const int2*)(ei + (size_t)E + e0);
        d0 = v.x;
        d1 = v.y;
      }
      atomicAdd(&counts[min(max(d0, 0), N - 1)], 1);
      if (has1) atomicAdd(&counts[min(max(d1, 0), N - 1)], 1);
    }
  }
  const int lane = tid & 63;
  const int wid = blockIdx.x * 4 + (tid >> 6);
  if (wid >= N) return;
  float f = ldv(x, (size_t)wid * D + lane, f32);
  prep_node(f, f32, wid, lane, W, att, fhat, Hmat, a_l, a_r);
}

// 3-pass multiblock exclusive scan
__global__ void k_scanA(const int* __restrict__ counts, int* __restrict__ row_ptr,
                        int* __restrict__ partials, int n) {
  __shared__ int sm[256];
  const int t = threadIdx.x;
  const int i = blockIdx.x * 256 + t;
  int v = (i < n) ? counts[i] : 0;
  sm[t] = v;
  __syncthreads();
  for (int off = 1; off < 256; off <<= 1) {
    int u = (t >= off) ? sm[t - off] : 0;
    __syncthreads();
    sm[t] += u;
    __syncthreads();
  }
  if (i < n) row_ptr[i] = sm[t] - v;
  if (t == 255) partials[blockIdx.x] = sm[255];
}
__global__ void __launch_bounds__(1024) k_scanB(int* __restrict__ partials,
                                                int* __restrict__ row_ptr,
                                                int nb, int n) {
  __shared__ int sm[1024];
  const int t = threadIdx.x;
  int v = (t < nb) ? partials[t] : 0;
  sm[t] = v;
  __syncthreads();
  for (int off = 1; off < 1024; off <<= 1) {
    int u = (t >= off) ? sm[t - off] : 0;
    __syncthreads();
    sm[t] += u;
    __syncthreads();
  }
  if (t < nb) partials[t] = sm[t] - v;
  if (t == nb - 1) row_ptr[n] = sm[t];
}
__global__ void k_scanC(int* __restrict__ row_ptr, int* __restrict__ wptr,
                        const int* __restrict__ partials, int n) {
  const int i = blockIdx.x * 256 + threadIdx.x;
  if (i < n) {
    int r = row_ptr[i] + partials[blockIdx.x];
    row_ptr[i] = r;
    wptr[i] = r;
  }
}

__global__ void k_fill(const int* __restrict__ ei, const void* __restrict__ w,
                       int E, int N, const int* __restrict__ flags,
                       int* __restrict__ wptr, unsigned int* __restrict__ csr) {
  int e0 = (blockIdx.x * blockDim.x + threadIdx.x) * 2;
  if (e0 >= E) return;
  const int wide = flags[1], f32 = flags[0];
  const bool has1 = (e0 + 1 < E);
  int s0, s1, d0, d1;
  if (wide) {
    int4 vs = *(const int4*)(ei + 2 * (size_t)e0);
    int4 vd = *(const int4*)(ei + 2 * (size_t)E + 2 * (size_t)e0);
    s0 = vs.x; s1 = vs.z; d0 = vd.x; d1 = vd.z;
  } else {
    int2 vs = *(const int2*)(ei + e0);
    int2 vd = *(const int2*)(ei + (size_t)E + e0);
    s0 = vs.x; s1 = vs.y; d0 = vd.x; d1 = vd.y;
  }
  float w0, w1 = 0.f;
  if (f32) {
    float2 wv = *(const float2*)((const float*)w + e0);
    w0 = wv.x; w1 = wv.y;
  } else {
    const __hip_bfloat16* wb = (const __hip_bfloat16*)w;
    w0 = __bfloat162float(wb[e0]);
    if (has1) w1 = __bfloat162float(wb[e0 + 1]);
  }
  float g0 = fminf(fmaxf(1.f - 0.25f * fminf(w0, 4.f), 0.f), 1.f);
  int p0 = atomicAdd(&wptr[min(max(d0, 0), N - 1)], 1);
  p0 = min(max(p0, 0), E - 1);
  csr[p0] = pack_sg(min(max(s0, 0), N - 1), g0);
  if (has1) {
    float g1 = fminf(fmaxf(1.f - 0.25f * fminf(w1, 4.f), 0.f), 1.f);
    int p1 = atomicAdd(&wptr[min(max(d1, 0), N - 1)], 1);
    p1 = min(max(p1, 0), E - 1);
    csr[p1] = pack_sg(min(max(s1, 0), N - 1), g1);
  }
}

// standalone prep (fallback path)
__global__ void __launch_bounds__(256) k_prep(const void* __restrict__ xin,
                                              const void* __restrict__ W,
                                              const void* __restrict__ att,
                                              const int* __restrict__ flags,
                                              unsigned char* __restrict__ fhat,
                                              __hip_bfloat16* __restrict__ Hmat,
                                              float* __restrict__ a_l,
                                              float* __restrict__ a_r, int N) {
  const int lane = threadIdx.x & 63;
  const int wid = (blockIdx.x * 256 + threadIdx.x) >> 6;
  if (wid >= N) return;
  const int f32 = flags[0];
  float f = ldv(xin, (size_t)wid * D + lane, f32);
  prep_node(f, f32, wid, lane, W, att, fhat, Hmat, a_l, a_r);
}

// ---------------- edge kernel: wave per dst node, 8-edge/8-lane groups ----------------
// R13: stage0 csr->regs, stage1 batch gathers (fhat+Hmat+a_r) in one latency
// exposure, Hmat held in registers across softmax; phase 3 is pure VALU.
__global__ void __launch_bounds__(256) k_edge(const int* __restrict__ row_ptr,
                                              const unsigned int* __restrict__ csr,
                                              _Float16* __restrict__ lbuf,
                                              _Float16* __restrict__ cbuf,
                                              const unsigned char* __restrict__ fhat,
                                              const __hip_bfloat16* __restrict__ Hmat,
                                              const float* __restrict__ a_l,
                                              const float* __restrict__ a_r,
                                              const void* __restrict__ beta,
                                              const void* __restrict__ bias,
                                              const void* __restrict__ x,
                                              const void* __restrict__ rW1,
                                              const void* __restrict__ rb1,
                                              const void* __restrict__ rW2,
                                              const void* __restrict__ rb2,
                                              const void* __restrict__ Wn,
                                              const void* __restrict__ attn,
                                              unsigned char* __restrict__ fh2,
                                              __hip_bfloat16* __restrict__ Hm2,
                                              float* __restrict__ al2,
                                              float* __restrict__ ar2,
                                              const int* __restrict__ flags,
                                              void* __restrict__ out,
                                              int N, int E, int mode) {
  const int lane = threadIdx.x & 63;
  const int wv = threadIdx.x >> 6;
  const int wid = blockIdx.x * 4 + wv;
  __shared__ float2 lds_lc[4][CAP];  // (l, c) per edge
  __shared__ float lds_p[4][CAP];    // final p per edge
  __shared__ float lds_t[4][D];
  if (wid >= N) return;
  const int f32 = flags[0];
  const int g = lane >> 3;   // edge slot in 8-edge group
  const int sub = lane & 7;  // feature block: [8*sub, 8*sub+8)
  int s0 = min(max(row_ptr[wid], 0), E);
  int e0 = min(max(row_ptr[wid + 1], s0), E);
  const int s = __builtin_amdgcn_readfirstlane(s0);
  const int deg = __builtin_amdgcn_readfirstlane(e0) - s;
  const int nk = min(deg, CAP);
  const int nblk = (nk + 7) >> 3;
  const float aln = a_l[wid];
  float2* lc = lds_lc[wv];
  float* sp = lds_p[wv];

  float fn[8];
  dec_fp8x8(((const uint2*)(fhat + (size_t)wid * D))[sub], fn);

  // ---- stage 0: batched csr loads -> regs (statically indexed) ----
  unsigned int myen = 0;
  if (lane < nk) myen = csr[s + lane];  // coalesced; feeds phase-2 gate
  unsigned int enr[8];
#pragma unroll
  for (int kk = 0; kk < 8; ++kk) {
    if (kk < nblk) {
      const int j = kk * 8 + g;
      unsigned int en = csr[s + min(j, deg - 1)];
      enr[kk] = (j < deg) ? en : (unsigned int)wid;  // dummy: src=wid
    }
  }

  // ---- stage 1: batch-issue ALL gathers in one latency exposure ----
  uint2 f8r[8];  // fhat fp8 rows (8B/lane)
  uint4 hm[8];   // Hmat bf16 rows (16B/lane) -- live until phase 3
  float arr[8];  // a_r[src]
#pragma unroll
  for (int kk = 0; kk < 8; ++kk) {
    if (kk < nblk) {
      const int src = upk_src(enr[kk], N);
      f8r[kk] = ((const uint2*)(fhat + (size_t)src * D))[sub];
      hm[kk] = ((const uint4*)(Hmat + (size_t)src * D))[sub];
      arr[kk] = a_r[src];
    }
  }

  // ---- stage 2: cos dots + GAT logits ----
  float m1 = -1e30f, m2 = -1e30f;
#pragma unroll
  for (int kk = 0; kk < 8; ++kk) {
    if (kk < nblk) {
      const int j = kk * 8 + g;
      float hv[8];
      dec_fp8x8(f8r[kk], hv);
      float d = 0.f;
#pragma unroll
      for (int i = 0; i < 8; ++i) d += fn[i] * hv[i];
      d += __shfl_xor(d, 1, 64);
      d += __shfl_xor(d, 2, 64);
      d += __shfl_xor(d, 4, 64);
      float l = aln + arr[kk];
      l = (l >= 0.f) ? l : NEG_SLOPE * l;
      if (j < deg) {
        m1 = fmaxf(m1, l);
        m2 = fmaxf(m2, d);
        if (sub == 0) lc[j] = make_float2(l, d);
      }
    }
  }
  // overflow edges (deg > CAP): old global path
  for (int base = CAP; base < deg; base += 8) {
    const int j = base + g;
    const bool val = j < deg;
    const unsigned int en = val ? csr[s + j] : (unsigned int)wid;
    const int src = upk_src(en, N);
    float hv[8];
    dec_fp8x8(((const uint2*)(fhat + (size_t)src * D))[sub], hv);
    float d = 0.f;
#pragma unroll
    for (int i = 0; i < 8; ++i) d += fn[i] * hv[i];
    d += __shfl_xor(d, 1, 64);
    d += __shfl_xor(d, 2, 64);
    d += __shfl_xor(d, 4, 64);
    float l = aln + a_r[src];
    l = (l >= 0.f) ? l : NEG_SLOPE * l;
    if (val) {
      m1 = fmaxf(m1, l);
      m2 = fmaxf(m2, d);
      if (sub == 0) {
        lbuf[s + j] = (_Float16)l;
        cbuf[s + j] = (_Float16)d;
      }
    }
  }
  m1 = fmaxf(m1, __shfl_xor(m1, 8, 64));
  m1 = fmaxf(m1, __shfl_xor(m1, 16, 64));
  m1 = fmaxf(m1, __shfl_xor(m1, 32, 64));
  m2 = fmaxf(m2, __shfl_xor(m2, 8, 64));
  m2 = fmaxf(m2, __shfl_xor(m2, 16, 64));
  m2 = fmaxf(m2, __shfl_xor(m2, 32, 64));

  // ---- phase 2: two softmax sums, then fused p ----
  float el0 = 0.f, ec0 = 0.f, gg0 = 0.f;
  float ps1 = 0.f, ps2 = 0.f;
  if (lane < nk) {
    gg0 = upk_gate(myen);
    float2 t = lc[lane];
    el0 = __expf(t.x - m1);
    ec0 = __expf(t.y - m2);
    ps1 += el0;
    ps2 += ec0;
  }
  for (int c = 1; c * 64 < deg; ++c) {
    const int j = c * 64 + lane;
    if (j < deg) {
      ps1 += __expf((float)lbuf[s + j] - m1);
      ps2 += __expf((float)cbuf[s + j] - m2);
    }
  }
  const float rs1 = 1.f / (wred_sum(ps1) + EPS_SM);
  const float rs2 = 1.f / (wred_sum(ps2) + EPS_SM);
  const float bb = 1.f / (1.f + __expf(-ldv(beta, 0, f32)));
  const float ob = 1.f - bb;

  float spv = 0.f;
  if (lane < nk) {
    float tt = (ob * el0 * rs1 + bb * ec0 * rs2) * gg0;
    float p0 = __expf(tt - 1.f);
    spv += p0;
    sp[lane] = p0;
  }
  for (int c = 1; c * 64 < deg; ++c) {  // overflow: recompute, stash p in lbuf
    const int j = c * 64 + lane;
    if (j < deg) {
      float elx = __expf((float)lbuf[s + j] - m1);
      float ecx = __expf((float)cbuf[s + j] - m2);
      float gx = upk_gate(csr[s + j]);
      float px = __expf((ob * elx * rs1 + bb * ecx * rs2) * gx - 1.f);
      lbuf[s + j] = (_Float16)px;
      spv += px;
    }
  }
  const float rinv = 1.f / (wred_sum(spv) + EPS_SM);

  // ---- phase 3: pure-VALU accumulate from register-resident Hmat rows ----
  float acc[8] = {0.f, 0.f, 0.f, 0.f, 0.f, 0.f, 0.f, 0.f};
  float pr[8];
#pragma unroll
  for (int kk = 0; kk < 8; ++kk) {
    if (kk < nblk) {
      const int j = kk * 8 + g;
      pr[kk] = (j < deg) ? sp[j] : 0.f;
    }
  }
#pragma unroll
  for (int kk = 0; kk < 8; ++kk) {
    if (kk < nblk) {
      float hv[8];
      unp8(hm[kk], hv);
      const float pv = pr[kk];
#pragma unroll
      for (int i = 0; i < 8; ++i) acc[i] += pv * hv[i];
    }
  }
  // overflow edges: gather Hmat as before
  for (int base = CAP; base < deg; base += 8) {
    const int j = base + g;
    float pv;
    int srcv;
    if (j >= deg) {
      pv = 0.f;
      srcv = wid;
    } else {
      pv = (float)lbuf[s + j];
      srcv = upk_src(csr[s + j], N);
    }
    float hv[8];
    unp8(((const uint4*)(Hmat + (size_t)srcv * D))[sub], hv);
#pragma unroll
    for (int i = 0; i < 8; ++i) acc[i] += pv * hv[i];
  }
#pragma unroll
  for (int i = 0; i < 8; ++i) {
    acc[i] += __shfl_xor(acc[i], 8, 64);
    acc[i] += __shfl_xor(acc[i], 16, 64);
    acc[i] += __shfl_xor(acc[i], 32, 64);
  }
  if (g == 0) {
#pragma unroll
    for (int i = 0; i < 8; ++i) lds_t[wv][8 * sub + i] = acc[i];
  }
  float v = lds_t[wv][lane] * rinv + ldv(bias, lane, f32);
  v = elu1(v);  // elu inside _cosgat
  if (mode == 1) {
    // fused residual MLP: relu(x@rW1+rb1)@rW2+rb2
    float xv = ldv(x, (size_t)wid * D + lane, f32);
    float a1 = ldv(rb1, lane, f32);
    float a2;
    if (f32) {
      const float* w1 = (const float*)rW1;
      const float* w2 = (const float*)rW2;
#pragma unroll 8
      for (int k = 0; k < D; ++k) a1 += __shfl(xv, k, 64) * w1[k * D + lane];
      float tr = fmaxf(a1, 0.f);
      a2 = ((const float*)rb2)[lane];
#pragma unroll 8
      for (int k = 0; k < D; ++k) a2 += __shfl(tr, k, 64) * w2[k * D + lane];
    } else {
      const __hip_bfloat16* w1 = (const __hip_bfloat16*)rW1;
      const __hip_bfloat16* w2 = (const __hip_bfloat16*)rW2;
#pragma unroll 8
      for (int k = 0; k < D; ++k) a1 += __shfl(xv, k, 64) * __bfloat162float(w1[k * D + lane]);
      float tr = fmaxf(a1, 0.f);
      a2 = __bfloat162float(((const __hip_bfloat16*)rb2)[lane]);
#pragma unroll 8
      for (int k = 0; k < D; ++k) a2 += __shfl(tr, k, 64) * __bfloat162float(w2[k * D + lane]);
    }
    stv(out, (size_t)wid * D + lane, f32, sane(v + a2));
  } else {
    v = elu1(v);  // inter-layer elu
    if (mode == 0) {
      prep_node(sane(v), f32, wid, lane, Wn, attn, fh2, Hm2, al2, ar2);
    } else {
      stv(out, (size_t)wid * D + lane, f32, sane(v));
    }
  }
}

extern "C" void kernel_launch(void* const* d_in, const int* in_sizes, int n_in,
                              void* d_out, int out_size, void* d_ws, size_t ws_size,
                              hipStream_t stream) {
  const void* x = d_in[0];
  const int* ei = (const int*)d_in[1];
  const void* w = d_in[2];
  const void* W0 = d_in[3];
  const void* att0 = d_in[4];
  const void* beta0 = d_in[5];
  const void* b0 = d_in[6];
  const void* W1 = d_in[7];
  const void* att1 = d_in[8];
  const void* beta1 = d_in[9];
  const void* b1 = d_in[10];
  const void* rW1 = d_in[11];
  const void* rb1 = d_in[12];
  const void* rW2 = d_in[13];
  const void* rb2 = d_in[14];

  const int N = in_sizes[0] / D;
  const int E = in_sizes[2];

  char* base = (char*)d_ws;
  size_t off = 0;
  auto alloc = [&](size_t bytes) -> void* {
    void* p = base + off;
    off += (bytes + 255) & ~(size_t)255;
    return p;
  };
  int* flags = (int*)alloc(256);
  int* partials = (int*)alloc(1024 * 4);
  int* counts = (int*)alloc((size_t)N * 4);
  int* wptr = (int*)alloc((size_t)N * 4);
  int* row_ptr = (int*)alloc((size_t)(N + 1) * 4);
  unsigned int* csr = (unsigned int*)alloc((size_t)E * 4);
  _Float16* lbuf = (_Float16*)alloc((size_t)E * 2);
  _Float16* cbuf = (_Float16*)alloc((size_t)E * 2);
  unsigned char* fhat = (unsigned char*)alloc((size_t)N * D);
  __hip_bfloat16* Hmat = (__hip_bfloat16*)alloc((size_t)N * D * 2);
  float* a_l = (float*)alloc((size_t)N * 4);
  float* a_r = (float*)alloc((size_t)N * 4);
  unsigned char* fhat2 = (unsigned char*)alloc((size_t)N * D);
  __hip_bfloat16* Hmat2 = (__hip_bfloat16*)alloc((size_t)N * D * 2);
  float* a_l2 = (float*)alloc((size_t)N * 4);
  float* a_r2 = (float*)alloc((size_t)N * 4);
  const bool fused = (off <= ws_size);

  const int eb2 = (E / 2 + 255) / 256;
  const int nb = (N + 3) / 4;
  const int sb = (N + 255) / 256;

  hipMemsetAsync(counts, 0, (size_t)N * 4, stream);
  k_init<<<nb, 256, 0, stream>>>((const unsigned short*)x, ei, flags, counts,
                                 x, W0, att0, fhat, Hmat, a_l, a_r, N, E);
  k_scanA<<<sb, 256, 0, stream>>>(counts, row_ptr, partials, N);
  k_scanB<<<1, 1024, 0, stream>>>(partials, row_ptr, sb, N);
  k_scanC<<<sb, 256, 0, stream>>>(row_ptr, wptr, partials, N);
  k_fill<<<eb2, 256, 0, stream>>>(ei, w, E, N, flags, wptr, csr);

  if (fused) {
    k_edge<<<nb, 256, 0, stream>>>(row_ptr, csr, lbuf, cbuf, fhat, Hmat, a_l, a_r,
                                   beta0, b0, x, rW1, rb1, rW2, rb2,
                                   W1, att1, fhat2, Hmat2, a_l2, a_r2,
                                   flags, d_out, N, E, 0);
    k_edge<<<nb, 256, 0, stream>>>(row_ptr, csr, lbuf, cbuf, fhat2, Hmat2, a_l2, a_r2,
                                   beta1, b1, x, rW1, rb1, rW2, rb2,
                                   nullptr, nullptr, nullptr, nullptr, nullptr, nullptr,
                                   flags, d_out, N, E, 1);
  } else {
    k_edge<<<nb, 256, 0, stream>>>(row_ptr, csr, lbuf, cbuf, fhat, Hmat, a_l, a_r,
                                   beta0, b0, x, rW1, rb1, rW2, rb2,
                                   nullptr, nullptr, nullptr, nullptr, nullptr, nullptr,
                                   flags, d_out, N, E, 2);
    k_prep<<<nb, 256, 0, stream>>>(d_out, W1, att1, flags, fhat, Hmat, a_l, a_r, N);
    k_edge<<<nb, 256, 0, stream>>>(row_ptr, csr, lbuf, cbuf, fhat, Hmat, a_l, a_r,
                                   beta1, b1, x, rW1, rb1, rW2, rb2,
                                   nullptr, nullptr, nullptr, nullptr, nullptr, nullptr,
                                   flags, d_out, N, E, 1);
  }
}

// Round 2
// 510.653 us; speedup vs baseline: 1.0172x; 1.0172x over previous
//
#include <hip/hip_runtime.h>
#include <hip/hip_bf16.h>
#include <math.h>

// COSGATEncoder: N=50000, E=1280000, D=64, HEADS=1. f32 in/out (runtime-detected,
// bf16 fallback), edge_index int64 (runtime-detected, int32 fallback).
// R14: revert to R12 k_edge structure (R13's register-batched gathers spilled to
// scratch: VGPR=52 w/ ~72 live regs, occupancy 70->41%, dur +9%). New: phase 1
// co-issues the Hmat row gather with the fhat gather and lands it in LDS
// (CAPH=32 edges x 128B x 4 waves = 16KB; total LDS 21.5KB -> 7 blocks/CU =
// 87.5% occupancy ceiling). Phase 3 reads Hmat from LDS (contiguous ds_read_b128,
// conflict-free) for ~98% of edges, removing the second dependent global-gather
// latency exposure. Rest = R12 (fp8 fhat rows, packed 4B csr, fused epilogues).

constexpr int D = 64;
constexpr int CAP = 64;
constexpr int CAPH = 32;  // edges whose Hmat row is staged in LDS
constexpr float NEG_SLOPE = 0.2f;
constexpr float EPS_COS = 1e-8f;
constexpr float EPS_SM = 1e-16f;

#if defined(__has_builtin)
#if __has_builtin(__builtin_amdgcn_cvt_pk_f32_fp8) && __has_builtin(__builtin_amdgcn_cvt_pk_fp8_f32)
#define HW_FP8 1
#endif
#endif

typedef float floatx2 __attribute__((ext_vector_type(2)));

__device__ __forceinline__ float wred_sum(float v) {
#pragma unroll
  for (int off = 32; off > 0; off >>= 1) v += __shfl_xor(v, off, 64);
  return v;
}
__device__ __forceinline__ float elu1(float x) { return x > 0.f ? x : __expf(x) - 1.f; }
__device__ __forceinline__ float sane(float v) {
  return (v == v && fabsf(v) < 1e30f) ? v : 0.f;
}
__device__ __forceinline__ float ldv(const void* p, size_t i, int f32) {
  return f32 ? ((const float*)p)[i]
             : __bfloat162float(((const __hip_bfloat16*)p)[i]);
}
__device__ __forceinline__ void stv(void* p, size_t i, int f32, float v) {
  if (f32) ((float*)p)[i] = v;
  else ((__hip_bfloat16*)p)[i] = __float2bfloat16(v);
}
__device__ __forceinline__ float b2f(unsigned short u) {
  return __uint_as_float(((unsigned int)u) << 16);
}
__device__ __forceinline__ void unp8(uint4 u, float* f) {
  f[0] = __uint_as_float(u.x << 16);
  f[1] = __uint_as_float(u.x & 0xffff0000u);
  f[2] = __uint_as_float(u.y << 16);
  f[3] = __uint_as_float(u.y & 0xffff0000u);
  f[4] = __uint_as_float(u.z << 16);
  f[5] = __uint_as_float(u.z & 0xffff0000u);
  f[6] = __uint_as_float(u.w << 16);
  f[7] = __uint_as_float(u.w & 0xffff0000u);
}

// ---- fp8 helpers: HW e4m3 when available, f16-msb (e5m2-like) fallback ----
__device__ __forceinline__ unsigned char enc_fp8(float v) {
#ifdef HW_FP8
  int pk = __builtin_amdgcn_cvt_pk_fp8_f32(v, v, 0, false);
  return (unsigned char)(pk & 0xFF);
#else
  _Float16 h = (_Float16)v;
  unsigned short ub;
  __builtin_memcpy(&ub, &h, 2);
  return (unsigned char)((ub + 0x80) >> 8);  // RNE-ish truncate to top byte
#endif
}
__device__ __forceinline__ void dec_fp8x8(uint2 u, float* f) {
#ifdef HW_FP8
  floatx2 a = __builtin_amdgcn_cvt_pk_f32_fp8(u.x, false);
  floatx2 b = __builtin_amdgcn_cvt_pk_f32_fp8(u.x, true);
  floatx2 c = __builtin_amdgcn_cvt_pk_f32_fp8(u.y, false);
  floatx2 d = __builtin_amdgcn_cvt_pk_f32_fp8(u.y, true);
  f[0] = a[0]; f[1] = a[1]; f[2] = b[0]; f[3] = b[1];
  f[4] = c[0]; f[5] = c[1]; f[6] = d[0]; f[7] = d[1];
#else
#pragma unroll
  for (int i = 0; i < 8; ++i) {
    unsigned int byte = (i < 4 ? (u.x >> (8 * i)) : (u.y >> (8 * (i - 4)))) & 0xFF;
    unsigned short hb = (unsigned short)(byte << 8);
    _Float16 h;
    __builtin_memcpy(&h, &hb, 2);
    f[i] = (float)h;
  }
#endif
}

// packed csr entry: bits 0..17 = src, bits 18..31 = gate quantized to 14 bits
__device__ __forceinline__ unsigned int pack_sg(int src, float g) {
  int gq = (int)(g * 16383.f + 0.5f);
  return ((unsigned int)src & 0x3FFFFu) | ((unsigned int)gq << 18);
}
__device__ __forceinline__ int upk_src(unsigned int e, int N) {
  return min((int)(e & 0x3FFFFu), N - 1);
}
__device__ __forceinline__ float upk_gate(unsigned int e) {
  return (float)(e >> 18) * (1.f / 16383.f);
}

// shared prep body: node features (lane=feature) -> fhat(fp8), Hmat(bf16), a_l, a_r
__device__ __forceinline__ void prep_node(float f, int f32, int wid, int lane,
                                          const void* __restrict__ W,
                                          const void* __restrict__ att,
                                          unsigned char* __restrict__ fhat,
                                          __hip_bfloat16* __restrict__ Hmat,
                                          float* __restrict__ a_l,
                                          float* __restrict__ a_r) {
  float n2 = wred_sum(f * f);
  float nrm = fmaxf(sqrtf(n2), EPS_COS);
  fhat[(size_t)wid * D + lane] = enc_fp8(f / nrm);
  float Hc = 0.f;
  if (f32) {
    const float* Wf = (const float*)W;
#pragma unroll 8
    for (int k = 0; k < D; ++k) Hc += __shfl(f, k, 64) * Wf[k * D + lane];
  } else {
    const __hip_bfloat16* Wb = (const __hip_bfloat16*)W;
#pragma unroll 8
    for (int k = 0; k < D; ++k) Hc += __shfl(f, k, 64) * __bfloat162float(Wb[k * D + lane]);
  }
  Hmat[(size_t)wid * D + lane] = __float2bfloat16(Hc);
  float al = wred_sum(Hc * ldv(att, lane, f32));
  float ar = wred_sum(Hc * ldv(att, D + lane, f32));
  if (lane == 0) {
    a_l[wid] = al;
    a_r[wid] = ar;
  }
}

// fused: per-block dtype detect + degree count + layer-0 prep
__global__ void __launch_bounds__(256) k_init(const unsigned short* __restrict__ xu,
                                              const int* __restrict__ ei,
                                              int* __restrict__ flags,
                                              int* __restrict__ counts,
                                              const void* __restrict__ x,
                                              const void* __restrict__ W,
                                              const void* __restrict__ att,
                                              unsigned char* __restrict__ fhat,
                                              __hip_bfloat16* __restrict__ Hmat,
                                              float* __restrict__ a_l,
                                              float* __restrict__ a_r, int N, int E) {
  __shared__ int sf[2];
  const int tid = threadIdx.x;
  if (tid < 64) {
    float v = b2f(xu[tid]);
    float a = fabsf(v);
    unsigned long long m = __ballot(a > 1e-4f && a < 100.f);
    unsigned long long m2 = __ballot(ei[2 * tid + 1] != 0);
    if (tid == 0) {
      sf[0] = (__popcll(m) >= 60) ? 0 : 1;  // 1 => f32
      sf[1] = (m2 == 0ull) ? 1 : 0;         // 1 => int64
      if (blockIdx.x == 0) {
        flags[0] = sf[0];
        flags[1] = sf[1];
      }
    }
  }
  __syncthreads();
  const int f32 = sf[0], wide = sf[1];
  {
    const int e0 = (blockIdx.x * 256 + tid) * 2;
    if (e0 < E) {
      int d0, d1;
      const bool has1 = (e0 + 1 < E);
      if (wide) {
        int4 v = *(const int4*)(ei + 2 * (size_t)E + 2 * (size_t)e0);
        d0 = v.x;
        d1 = v.z;
      } else {
        int2 v = *(const int2*)(ei + (size_t)E + e0);
        d0 = v.x;
        d1 = v.y;
      }
      atomicAdd(&counts[min(max(d0, 0), N - 1)], 1);
      if (has1) atomicAdd(&counts[min(max(d1, 0), N - 1)], 1);
    }
  }
  const int lane = tid & 63;
  const int wid = blockIdx.x * 4 + (tid >> 6);
  if (wid >= N) return;
  float f = ldv(x, (size_t)wid * D + lane, f32);
  prep_node(f, f32, wid, lane, W, att, fhat, Hmat, a_l, a_r);
}

// 3-pass multiblock exclusive scan
__global__ void k_scanA(const int* __restrict__ counts, int* __restrict__ row_ptr,
                        int* __restrict__ partials, int n) {
  __shared__ int sm[256];
  const int t = threadIdx.x;
  const int i = blockIdx.x * 256 + t;
  int v = (i < n) ? counts[i] : 0;
  sm[t] = v;
  __syncthreads();
  for (int off = 1; off < 256; off <<= 1) {
    int u = (t >= off) ? sm[t - off] : 0;
    __syncthreads();
    sm[t] += u;
    __syncthreads();
  }
  if (i < n) row_ptr[i] = sm[t] - v;
  if (t == 255) partials[blockIdx.x] = sm[255];
}
__global__ void __launch_bounds__(1024) k_scanB(int* __restrict__ partials,
                                                int* __restrict__ row_ptr,
                                                int nb, int n) {
  __shared__ int sm[1024];
  const int t = threadIdx.x;
  int v = (t < nb) ? partials[t] : 0;
  sm[t] = v;
  __syncthreads();
  for (int off = 1; off < 1024; off <<= 1) {
    int u = (t >= off) ? sm[t - off] : 0;
    __syncthreads();
    sm[t] += u;
    __syncthreads();
  }
  if (t < nb) partials[t] = sm[t] - v;
  if (t == nb - 1) row_ptr[n] = sm[t];
}
__global__ void k_scanC(int* __restrict__ row_ptr, int* __restrict__ wptr,
                        const int* __restrict__ partials, int n) {
  const int i = blockIdx.x * 256 + threadIdx.x;
  if (i < n) {
    int r = row_ptr[i] + partials[blockIdx.x];
    row_ptr[i] = r;
    wptr[i] = r;
  }
}

__global__ void k_fill(const int* __restrict__ ei, const void* __restrict__ w,
                       int E, int N, const int* __restrict__ flags,
                       int* __restrict__ wptr, unsigned int* __restrict__ csr) {
  int e0 = (blockIdx.x * blockDim.x + threadIdx.x) * 2;
  if (e0 >= E) return;
  const int wide = flags[1], f32 = flags[0];
  const bool has1 = (e0 + 1 < E);
  int s0, s1, d0, d1;
  if (wide) {
    int4 vs = *(const int4*)(ei + 2 * (size_t)e0);
    int4 vd = *(const int4*)(ei + 2 * (size_t)E + 2 * (size_t)e0);
    s0 = vs.x; s1 = vs.z; d0 = vd.x; d1 = vd.z;
  } else {
    int2 vs = *(const int2*)(ei + e0);
    int2 vd = *(const int2*)(ei + (size_t)E + e0);
    s0 = vs.x; s1 = vs.y; d0 = vd.x; d1 = vd.y;
  }
  float w0, w1 = 0.f;
  if (f32) {
    float2 wv = *(const float2*)((const float*)w + e0);
    w0 = wv.x; w1 = wv.y;
  } else {
    const __hip_bfloat16* wb = (const __hip_bfloat16*)w;
    w0 = __bfloat162float(wb[e0]);
    if (has1) w1 = __bfloat162float(wb[e0 + 1]);
  }
  float g0 = fminf(fmaxf(1.f - 0.25f * fminf(w0, 4.f), 0.f), 1.f);
  int p0 = atomicAdd(&wptr[min(max(d0, 0), N - 1)], 1);
  p0 = min(max(p0, 0), E - 1);
  csr[p0] = pack_sg(min(max(s0, 0), N - 1), g0);
  if (has1) {
    float g1 = fminf(fmaxf(1.f - 0.25f * fminf(w1, 4.f), 0.f), 1.f);
    int p1 = atomicAdd(&wptr[min(max(d1, 0), N - 1)], 1);
    p1 = min(max(p1, 0), E - 1);
    csr[p1] = pack_sg(min(max(s1, 0), N - 1), g1);
  }
}

// standalone prep (fallback path)
__global__ void __launch_bounds__(256) k_prep(const void* __restrict__ xin,
                                              const void* __restrict__ W,
                                              const void* __restrict__ att,
                                              const int* __restrict__ flags,
                                              unsigned char* __restrict__ fhat,
                                              __hip_bfloat16* __restrict__ Hmat,
                                              float* __restrict__ a_l,
                                              float* __restrict__ a_r, int N) {
  const int lane = threadIdx.x & 63;
  const int wid = (blockIdx.x * 256 + threadIdx.x) >> 6;
  if (wid >= N) return;
  const int f32 = flags[0];
  float f = ldv(xin, (size_t)wid * D + lane, f32);
  prep_node(f, f32, wid, lane, W, att, fhat, Hmat, a_l, a_r);
}

// ---------------- edge kernel: wave per dst node, 8-edge/8-lane groups ----------------
// R14: phase 1 co-issues Hmat gather with fhat gather, stages rows in LDS
// (first CAPH edges); phase 3 consumes from LDS -> one latency zone, not two.
__global__ void __launch_bounds__(256) k_edge(const int* __restrict__ row_ptr,
                                              const unsigned int* __restrict__ csr,
                                              _Float16* __restrict__ lbuf,
                                              _Float16* __restrict__ cbuf,
                                              const unsigned char* __restrict__ fhat,
                                              const __hip_bfloat16* __restrict__ Hmat,
                                              const float* __restrict__ a_l,
                                              const float* __restrict__ a_r,
                                              const void* __restrict__ beta,
                                              const void* __restrict__ bias,
                                              const void* __restrict__ x,
                                              const void* __restrict__ rW1,
                                              const void* __restrict__ rb1,
                                              const void* __restrict__ rW2,
                                              const void* __restrict__ rb2,
                                              const void* __restrict__ Wn,
                                              const void* __restrict__ attn,
                                              unsigned char* __restrict__ fh2,
                                              __hip_bfloat16* __restrict__ Hm2,
                                              float* __restrict__ al2,
                                              float* __restrict__ ar2,
                                              const int* __restrict__ flags,
                                              void* __restrict__ out,
                                              int N, int E, int mode) {
  const int lane = threadIdx.x & 63;
  const int wv = threadIdx.x >> 6;
  const int wid = blockIdx.x * 4 + wv;
  __shared__ float2 lds_lc[4][CAP];        // (l, c)
  __shared__ float2 lds_sg[4][CAP];        // (packed bits, -) -> later (src bits, p)
  __shared__ float lds_t[4][D];
  __shared__ uint4 lds_hm[4][CAPH][8];     // staged Hmat rows (bf16x8 per uint4)
  if (wid >= N) return;
  const int f32 = flags[0];
  const int g = lane >> 3;   // edge slot in 8-edge group
  const int sub = lane & 7;  // feature block: [8*sub, 8*sub+8)
  const int s = min(max(row_ptr[wid], 0), E);
  const int e = min(max(row_ptr[wid + 1], s), E);
  const int deg = e - s;
  const float aln = a_l[wid];
  float2* lc = lds_lc[wv];
  float2* sg = lds_sg[wv];
  uint4 (*hmw)[8] = lds_hm[wv];

  float fn[8];
  dec_fp8x8(((const uint2*)(fhat + (size_t)wid * D))[sub], fn);

  // ---- phase 1: 8 edges/iter (unroll 4); fp8 row gathers + Hmat stage to LDS ----
  float m1 = -1e30f, m2 = -1e30f;
#pragma unroll 4
  for (int base = 0; base < deg; base += 8) {
    const int j = base + g;
    const bool val = j < deg;
    const unsigned int en = val ? csr[s + j] : (unsigned int)wid;
    const int src = upk_src(en, N);
    // issue both gathers back-to-back so they fly together
    uint2 f8 = ((const uint2*)(fhat + (size_t)src * D))[sub];
    uint4 hmr = make_uint4(0u, 0u, 0u, 0u);
    if (base < CAPH) hmr = ((const uint4*)(Hmat + (size_t)src * D))[sub];
    float arv = a_r[src];
    float hv[8];
    dec_fp8x8(f8, hv);
    float d = 0.f;
#pragma unroll
    for (int i = 0; i < 8; ++i) d += fn[i] * hv[i];
    d += __shfl_xor(d, 1, 64);
    d += __shfl_xor(d, 2, 64);
    d += __shfl_xor(d, 4, 64);
    float l = aln + arv;
    l = (l >= 0.f) ? l : NEG_SLOPE * l;
    if (base < CAPH) hmw[j][sub] = hmr;  // j = base+g <= 24+7 = 31 < CAPH
    if (val) {
      m1 = fmaxf(m1, l);
      m2 = fmaxf(m2, d);
      if (sub == 0) {
        if (j < CAP) {
          lc[j] = make_float2(l, d);
          sg[j] = make_float2(__uint_as_float(en), 0.f);
        } else {
          lbuf[s + j] = (_Float16)l;
          cbuf[s + j] = (_Float16)d;
        }
      }
    }
  }
  m1 = fmaxf(m1, __shfl_xor(m1, 8, 64));
  m1 = fmaxf(m1, __shfl_xor(m1, 16, 64));
  m1 = fmaxf(m1, __shfl_xor(m1, 32, 64));
  m2 = fmaxf(m2, __shfl_xor(m2, 8, 64));
  m2 = fmaxf(m2, __shfl_xor(m2, 16, 64));
  m2 = fmaxf(m2, __shfl_xor(m2, 32, 64));

  // ---- merged phase 2 + 3-prep: chunk 0 via LDS (deg<=64 typical), rest global ----
  float el0 = 0.f, ec0 = 0.f, gg0 = 0.f;
  int q0 = 0;
  float ps1 = 0.f, ps2 = 0.f;
  if (lane < deg) {
    unsigned int en = __float_as_uint(sg[lane].x);
    q0 = upk_src(en, N);
    gg0 = upk_gate(en);
    float2 t = lc[lane];
    el0 = __expf(t.x - m1);
    ec0 = __expf(t.y - m2);
    ps1 += el0;
    ps2 += ec0;
  }
  for (int c = 1; c * 64 < deg; ++c) {
    const int j = c * 64 + lane;
    if (j < deg) {
      ps1 += __expf((float)lbuf[s + j] - m1);
      ps2 += __expf((float)cbuf[s + j] - m2);
    }
  }
  const float rs1 = 1.f / (wred_sum(ps1) + EPS_SM);
  const float rs2 = 1.f / (wred_sum(ps2) + EPS_SM);
  const float bb = 1.f / (1.f + __expf(-ldv(beta, 0, f32)));
  const float ob = 1.f - bb;

  float sp = 0.f;
  if (lane < deg) {
    float tt = (ob * el0 * rs1 + bb * ec0 * rs2) * gg0;
    float p0 = __expf(tt - 1.f);
    sp += p0;
    sg[lane] = make_float2(__int_as_float(q0), p0);  // (src, p)
  }
  for (int c = 1; c * 64 < deg; ++c) {  // overflow: recompute, stash p in lbuf
    const int j = c * 64 + lane;
    if (j < deg) {
      float elx = __expf((float)lbuf[s + j] - m1);
      float ecx = __expf((float)cbuf[s + j] - m2);
      float gx = upk_gate(csr[s + j]);
      float px = __expf((ob * elx * rs1 + bb * ecx * rs2) * gx - 1.f);
      lbuf[s + j] = (_Float16)px;
      sp += px;
    }
  }
  const float rinv = 1.f / (wred_sum(sp) + EPS_SM);

  // ---- phase 3 accumulate: Hmat from LDS for first CAPH edges, else global ----
  float acc[8] = {0.f, 0.f, 0.f, 0.f, 0.f, 0.f, 0.f, 0.f};
  if (deg <= CAP) {
#pragma unroll 4
    for (int base = 0; base < deg; base += 8) {
      const int j = base + g;
      float2 en = (j < deg) ? sg[j] : make_float2(__int_as_float(wid), 0.f);
      const float pv = en.y;
      float hv[8];
      if (base < CAPH) {
        unp8(hmw[j][sub], hv);  // staged in phase 1 (dummy rows ok: pv=0)
      } else {
        const int srcv = __float_as_int(en.x);
        unp8(((const uint4*)(Hmat + (size_t)srcv * D))[sub], hv);
      }
#pragma unroll
      for (int i = 0; i < 8; ++i) acc[i] += pv * hv[i];
    }
  } else {
    for (int base = 0; base < deg; base += 8) {
      const int j = base + g;
      float pv;
      int srcv;
      if (j >= deg) {
        pv = 0.f;
        srcv = wid;
      } else if (j < CAP) {
        float2 en = sg[j];
        pv = en.y;
        srcv = __float_as_int(en.x);
      } else {
        pv = (float)lbuf[s + j];
        srcv = upk_src(csr[s + j], N);
      }
      float hv[8];
      if (base < CAPH) {
        unp8(hmw[j][sub], hv);
      } else {
        unp8(((const uint4*)(Hmat + (size_t)srcv * D))[sub], hv);
      }
#pragma unroll
      for (int i = 0; i < 8; ++i) acc[i] += pv * hv[i];
    }
  }
#pragma unroll
  for (int i = 0; i < 8; ++i) {
    acc[i] += __shfl_xor(acc[i], 8, 64);
    acc[i] += __shfl_xor(acc[i], 16, 64);
    acc[i] += __shfl_xor(acc[i], 32, 64);
  }
  if (g == 0) {
#pragma unroll
    for (int i = 0; i < 8; ++i) lds_t[wv][8 * sub + i] = acc[i];
  }
  float v = lds_t[wv][lane] * rinv + ldv(bias, lane, f32);
  v = elu1(v);  // elu inside _cosgat
  if (mode == 1) {
    // fused residual MLP: relu(x@rW1+rb1)@rW2+rb2
    float xv = ldv(x, (size_t)wid * D + lane, f32);
    float a1 = ldv(rb1, lane, f32);
    float a2;
    if (f32) {
      const float* w1 = (const float*)rW1;
      const float* w2 = (const float*)rW2;
#pragma unroll 8
      for (int k = 0; k < D; ++k) a1 += __shfl(xv, k, 64) * w1[k * D + lane];
      float tr = fmaxf(a1, 0.f);
      a2 = ((const float*)rb2)[lane];
#pragma unroll 8
      for (int k = 0; k < D; ++k) a2 += __shfl(tr, k, 64) * w2[k * D + lane];
    } else {
      const __hip_bfloat16* w1 = (const __hip_bfloat16*)rW1;
      const __hip_bfloat16* w2 = (const __hip_bfloat16*)rW2;
#pragma unroll 8
      for (int k = 0; k < D; ++k) a1 += __shfl(xv, k, 64) * __bfloat162float(w1[k * D + lane]);
      float tr = fmaxf(a1, 0.f);
      a2 = __bfloat162float(((const __hip_bfloat16*)rb2)[lane]);
#pragma unroll 8
      for (int k = 0; k < D; ++k) a2 += __shfl(tr, k, 64) * __bfloat162float(w2[k * D + lane]);
    }
    stv(out, (size_t)wid * D + lane, f32, sane(v + a2));
  } else {
    v = elu1(v);  // inter-layer elu
    if (mode == 0) {
      prep_node(sane(v), f32, wid, lane, Wn, attn, fh2, Hm2, al2, ar2);
    } else {
      stv(out, (size_t)wid * D + lane, f32, sane(v));
    }
  }
}

extern "C" void kernel_launch(void* const* d_in, const int* in_sizes, int n_in,
                              void* d_out, int out_size, void* d_ws, size_t ws_size,
                              hipStream_t stream) {
  const void* x = d_in[0];
  const int* ei = (const int*)d_in[1];
  const void* w = d_in[2];
  const void* W0 = d_in[3];
  const void* att0 = d_in[4];
  const void* beta0 = d_in[5];
  const void* b0 = d_in[6];
  const void* W1 = d_in[7];
  const void* att1 = d_in[8];
  const void* beta1 = d_in[9];
  const void* b1 = d_in[10];
  const void* rW1 = d_in[11];
  const void* rb1 = d_in[12];
  const void* rW2 = d_in[13];
  const void* rb2 = d_in[14];

  const int N = in_sizes[0] / D;
  const int E = in_sizes[2];

  char* base = (char*)d_ws;
  size_t off = 0;
  auto alloc = [&](size_t bytes) -> void* {
    void* p = base + off;
    off += (bytes + 255) & ~(size_t)255;
    return p;
  };
  int* flags = (int*)alloc(256);
  int* partials = (int*)alloc(1024 * 4);
  int* counts = (int*)alloc((size_t)N * 4);
  int* wptr = (int*)alloc((size_t)N * 4);
  int* row_ptr = (int*)alloc((size_t)(N + 1) * 4);
  unsigned int* csr = (unsigned int*)alloc((size_t)E * 4);
  _Float16* lbuf = (_Float16*)alloc((size_t)E * 2);
  _Float16* cbuf = (_Float16*)alloc((size_t)E * 2);
  unsigned char* fhat = (unsigned char*)alloc((size_t)N * D);
  __hip_bfloat16* Hmat = (__hip_bfloat16*)alloc((size_t)N * D * 2);
  float* a_l = (float*)alloc((size_t)N * 4);
  float* a_r = (float*)alloc((size_t)N * 4);
  unsigned char* fhat2 = (unsigned char*)alloc((size_t)N * D);
  __hip_bfloat16* Hmat2 = (__hip_bfloat16*)alloc((size_t)N * D * 2);
  float* a_l2 = (float*)alloc((size_t)N * 4);
  float* a_r2 = (float*)alloc((size_t)N * 4);
  const bool fused = (off <= ws_size);

  const int eb2 = (E / 2 + 255) / 256;
  const int nb = (N + 3) / 4;
  const int sb = (N + 255) / 256;

  hipMemsetAsync(counts, 0, (size_t)N * 4, stream);
  k_init<<<nb, 256, 0, stream>>>((const unsigned short*)x, ei, flags, counts,
                                 x, W0, att0, fhat, Hmat, a_l, a_r, N, E);
  k_scanA<<<sb, 256, 0, stream>>>(counts, row_ptr, partials, N);
  k_scanB<<<1, 1024, 0, stream>>>(partials, row_ptr, sb, N);
  k_scanC<<<sb, 256, 0, stream>>>(row_ptr, wptr, partials, N);
  k_fill<<<eb2, 256, 0, stream>>>(ei, w, E, N, flags, wptr, csr);

  if (fused) {
    k_edge<<<nb, 256, 0, stream>>>(row_ptr, csr, lbuf, cbuf, fhat, Hmat, a_l, a_r,
                                   beta0, b0, x, rW1, rb1, rW2, rb2,
                                   W1, att1, fhat2, Hmat2, a_l2, a_r2,
                                   flags, d_out, N, E, 0);
    k_edge<<<nb, 256, 0, stream>>>(row_ptr, csr, lbuf, cbuf, fhat2, Hmat2, a_l2, a_r2,
                                   beta1, b1, x, rW1, rb1, rW2, rb2,
                                   nullptr, nullptr, nullptr, nullptr, nullptr, nullptr,
                                   flags, d_out, N, E, 1);
  } else {
    k_edge<<<nb, 256, 0, stream>>>(row_ptr, csr, lbuf, cbuf, fhat, Hmat, a_l, a_r,
                                   beta0, b0, x, rW1, rb1, rW2, rb2,
                                   nullptr, nullptr, nullptr, nullptr, nullptr, nullptr,
                                   flags, d_out, N, E, 2);
    k_prep<<<nb, 256, 0, stream>>>(d_out, W1, att1, flags, fhat, Hmat, a_l, a_r, N);
    k_edge<<<nb, 256, 0, stream>>>(row_ptr, csr, lbuf, cbuf, fhat, Hmat, a_l, a_r,
                                   beta1, b1, x, rW1, rb1, rW2, rb2,
                                   nullptr, nullptr, nullptr, nullptr, nullptr, nullptr,
                                   flags, d_out, N, E, 1);
  }
}

// Round 3
// 449.937 us; speedup vs baseline: 1.1545x; 1.1349x over previous
//
#include <hip/hip_runtime.h>
#include <hip/hip_bf16.h>
#include <math.h>

// COSGATEncoder: N=50000, E=1280000, D=64, HEADS=1. f32 in/out (runtime-detected,
// bf16 fallback), edge_index int64 (runtime-detected, int32 fallback).
// R15: slot-CSR. csr2[dst][CAP] with slot=atomicAdd(cnt[dst]) kills the
// count->scanA/B/C->fill pipeline (9 dispatches -> 4: memset, k_all, k_edge x2).
// k_all fuses dtype-detect + node prep + edge placement. deg>CAP handled by an
// exact 3-pass in-kernel fallback over the raw edge list (P~1e-10, never runs
// on bench data, keeps correctness for arbitrary input). lbuf/cbuf deleted.
// prep/MLP serial FMA chains split into 4 accumulators. k_edge phases = R12
// (best measured: 133.5us; R13 reg-batch spilled, R14 LDS-stage was neutral).

constexpr int D = 64;
constexpr int CAP = 64;
constexpr float NEG_SLOPE = 0.2f;
constexpr float EPS_COS = 1e-8f;
constexpr float EPS_SM = 1e-16f;

#if defined(__has_builtin)
#if __has_builtin(__builtin_amdgcn_cvt_pk_f32_fp8) && __has_builtin(__builtin_amdgcn_cvt_pk_fp8_f32)
#define HW_FP8 1
#endif
#endif

typedef float floatx2 __attribute__((ext_vector_type(2)));

__device__ __forceinline__ float wred_sum(float v) {
#pragma unroll
  for (int off = 32; off > 0; off >>= 1) v += __shfl_xor(v, off, 64);
  return v;
}
__device__ __forceinline__ float wred_max(float v) {
#pragma unroll
  for (int off = 32; off > 0; off >>= 1) v = fmaxf(v, __shfl_xor(v, off, 64));
  return v;
}
__device__ __forceinline__ float elu1(float x) { return x > 0.f ? x : __expf(x) - 1.f; }
__device__ __forceinline__ float sane(float v) {
  return (v == v && fabsf(v) < 1e30f) ? v : 0.f;
}
__device__ __forceinline__ float ldv(const void* p, size_t i, int f32) {
  return f32 ? ((const float*)p)[i]
             : __bfloat162float(((const __hip_bfloat16*)p)[i]);
}
__device__ __forceinline__ void stv(void* p, size_t i, int f32, float v) {
  if (f32) ((float*)p)[i] = v;
  else ((__hip_bfloat16*)p)[i] = __float2bfloat16(v);
}
__device__ __forceinline__ float b2f(unsigned short u) {
  return __uint_as_float(((unsigned int)u) << 16);
}
__device__ __forceinline__ void unp8(uint4 u, float* f) {
  f[0] = __uint_as_float(u.x << 16);
  f[1] = __uint_as_float(u.x & 0xffff0000u);
  f[2] = __uint_as_float(u.y << 16);
  f[3] = __uint_as_float(u.y & 0xffff0000u);
  f[4] = __uint_as_float(u.z << 16);
  f[5] = __uint_as_float(u.z & 0xffff0000u);
  f[6] = __uint_as_float(u.w << 16);
  f[7] = __uint_as_float(u.w & 0xffff0000u);
}

// ---- fp8 helpers: HW e4m3 when available, f16-msb (e5m2-like) fallback ----
__device__ __forceinline__ unsigned char enc_fp8(float v) {
#ifdef HW_FP8
  int pk = __builtin_amdgcn_cvt_pk_fp8_f32(v, v, 0, false);
  return (unsigned char)(pk & 0xFF);
#else
  _Float16 h = (_Float16)v;
  unsigned short ub;
  __builtin_memcpy(&ub, &h, 2);
  return (unsigned char)((ub + 0x80) >> 8);  // RNE-ish truncate to top byte
#endif
}
__device__ __forceinline__ void dec_fp8x8(uint2 u, float* f) {
#ifdef HW_FP8
  floatx2 a = __builtin_amdgcn_cvt_pk_f32_fp8(u.x, false);
  floatx2 b = __builtin_amdgcn_cvt_pk_f32_fp8(u.x, true);
  floatx2 c = __builtin_amdgcn_cvt_pk_f32_fp8(u.y, false);
  floatx2 d = __builtin_amdgcn_cvt_pk_f32_fp8(u.y, true);
  f[0] = a[0]; f[1] = a[1]; f[2] = b[0]; f[3] = b[1];
  f[4] = c[0]; f[5] = c[1]; f[6] = d[0]; f[7] = d[1];
#else
#pragma unroll
  for (int i = 0; i < 8; ++i) {
    unsigned int byte = (i < 4 ? (u.x >> (8 * i)) : (u.y >> (8 * (i - 4)))) & 0xFF;
    unsigned short hb = (unsigned short)(byte << 8);
    _Float16 h;
    __builtin_memcpy(&h, &hb, 2);
    f[i] = (float)h;
  }
#endif
}

// packed csr entry: bits 0..17 = src, bits 18..31 = gate quantized to 14 bits
__device__ __forceinline__ unsigned int pack_sg(int src, float g) {
  int gq = (int)(g * 16383.f + 0.5f);
  return ((unsigned int)src & 0x3FFFFu) | ((unsigned int)gq << 18);
}
__device__ __forceinline__ int upk_src(unsigned int e, int N) {
  return min((int)(e & 0x3FFFFu), N - 1);
}
__device__ __forceinline__ float upk_gate(unsigned int e) {
  return (float)(e >> 18) * (1.f / 16383.f);
}
__device__ __forceinline__ float gate_of(float w) {
  return fminf(fmaxf(1.f - 0.25f * fminf(w, 4.f), 0.f), 1.f);
}

// full fp8-row cosine dot (slow path only)
__device__ float slow_cos(const unsigned char* __restrict__ fhat, int a, int b) {
  const uint2* fa = (const uint2*)(fhat + (size_t)a * D);
  const uint2* fb = (const uint2*)(fhat + (size_t)b * D);
  float dsum = 0.f;
  for (int q = 0; q < 8; ++q) {
    float va[8], vb[8];
    dec_fp8x8(fa[q], va);
    dec_fp8x8(fb[q], vb);
#pragma unroll
    for (int i = 0; i < 8; ++i) dsum += va[i] * vb[i];
  }
  return dsum;
}

// shared prep body: node features (lane=feature) -> fhat(fp8), Hmat(bf16), a_l, a_r
__device__ __forceinline__ void prep_node(float f, int f32, int wid, int lane,
                                          const void* __restrict__ W,
                                          const void* __restrict__ att,
                                          unsigned char* __restrict__ fhat,
                                          __hip_bfloat16* __restrict__ Hmat,
                                          float* __restrict__ a_l,
                                          float* __restrict__ a_r) {
  float n2 = wred_sum(f * f);
  float nrm = fmaxf(sqrtf(n2), EPS_COS);
  fhat[(size_t)wid * D + lane] = enc_fp8(f / nrm);
  // 4 independent accumulator chains (dependent-FMA latency / 4)
  float h0 = 0.f, h1 = 0.f, h2 = 0.f, h3 = 0.f;
  if (f32) {
    const float* Wf = (const float*)W;
#pragma unroll 4
    for (int k = 0; k < D; k += 4) {
      h0 += __shfl(f, k, 64) * Wf[k * D + lane];
      h1 += __shfl(f, k + 1, 64) * Wf[(k + 1) * D + lane];
      h2 += __shfl(f, k + 2, 64) * Wf[(k + 2) * D + lane];
      h3 += __shfl(f, k + 3, 64) * Wf[(k + 3) * D + lane];
    }
  } else {
    const __hip_bfloat16* Wb = (const __hip_bfloat16*)W;
#pragma unroll 4
    for (int k = 0; k < D; k += 4) {
      h0 += __shfl(f, k, 64) * __bfloat162float(Wb[k * D + lane]);
      h1 += __shfl(f, k + 1, 64) * __bfloat162float(Wb[(k + 1) * D + lane]);
      h2 += __shfl(f, k + 2, 64) * __bfloat162float(Wb[(k + 2) * D + lane]);
      h3 += __shfl(f, k + 3, 64) * __bfloat162float(Wb[(k + 3) * D + lane]);
    }
  }
  float Hc = (h0 + h1) + (h2 + h3);
  Hmat[(size_t)wid * D + lane] = __float2bfloat16(Hc);
  float al = wred_sum(Hc * ldv(att, lane, f32));
  float ar = wred_sum(Hc * ldv(att, D + lane, f32));
  if (lane == 0) {
    a_l[wid] = al;
    a_r[wid] = ar;
  }
}

// fused: dtype detect + layer-0 prep + slot-CSR edge placement (one kernel)
__global__ void __launch_bounds__(256) k_all(const unsigned short* __restrict__ xu,
                                             const int* __restrict__ ei,
                                             const void* __restrict__ w,
                                             int* __restrict__ flags,
                                             int* __restrict__ cnt,
                                             const void* __restrict__ x,
                                             const void* __restrict__ W,
                                             const void* __restrict__ att,
                                             unsigned char* __restrict__ fhat,
                                             __hip_bfloat16* __restrict__ Hmat,
                                             float* __restrict__ a_l,
                                             float* __restrict__ a_r,
                                             unsigned int* __restrict__ csr2,
                                             int N, int E) {
  __shared__ int sf[2];
  const int tid = threadIdx.x;
  if (tid < 64) {
    float v = b2f(xu[tid]);
    float a = fabsf(v);
    unsigned long long m = __ballot(a > 1e-4f && a < 100.f);
    unsigned long long m2 = __ballot(ei[2 * tid + 1] != 0);
    if (tid == 0) {
      sf[0] = (__popcll(m) >= 60) ? 0 : 1;  // 1 => f32
      sf[1] = (m2 == 0ull) ? 1 : 0;         // 1 => int64
      if (blockIdx.x == 0) {
        flags[0] = sf[0];
        flags[1] = sf[1];
      }
    }
  }
  __syncthreads();
  const int f32 = sf[0], wide = sf[1];
  // ---- edge placement: 2 edges/thread, slot via atomicAdd on cnt[dst] ----
  {
    const int e0 = (blockIdx.x * 256 + tid) * 2;
    if (e0 < E) {
      const bool has1 = (e0 + 1 < E);
      int s0, s1, d0, d1;
      if (wide) {
        int4 vs = *(const int4*)(ei + 2 * (size_t)e0);
        int4 vd = *(const int4*)(ei + 2 * (size_t)E + 2 * (size_t)e0);
        s0 = vs.x; s1 = vs.z; d0 = vd.x; d1 = vd.z;
      } else {
        int2 vs = *(const int2*)(ei + e0);
        int2 vd = *(const int2*)(ei + (size_t)E + e0);
        s0 = vs.x; s1 = vs.y; d0 = vd.x; d1 = vd.y;
      }
      float w0, w1 = 0.f;
      if (f32) {
        float2 wv = *(const float2*)((const float*)w + e0);
        w0 = wv.x; w1 = wv.y;
      } else {
        const __hip_bfloat16* wb = (const __hip_bfloat16*)w;
        w0 = __bfloat162float(wb[e0]);
        if (has1) w1 = __bfloat162float(wb[e0 + 1]);
      }
      int d0c = min(max(d0, 0), N - 1);
      int slot0 = atomicAdd(&cnt[d0c], 1);
      if (slot0 < CAP) csr2[(size_t)d0c * CAP + slot0] = pack_sg(min(max(s0, 0), N - 1), gate_of(w0));
      if (has1) {
        int d1c = min(max(d1, 0), N - 1);
        int slot1 = atomicAdd(&cnt[d1c], 1);
        if (slot1 < CAP) csr2[(size_t)d1c * CAP + slot1] = pack_sg(min(max(s1, 0), N - 1), gate_of(w1));
      }
    }
  }
  // ---- node prep: wave per node ----
  const int lane = tid & 63;
  const int wid = blockIdx.x * 4 + (tid >> 6);
  if (wid >= N) return;
  float f = ldv(x, (size_t)wid * D + lane, f32);
  prep_node(f, f32, wid, lane, W, att, fhat, Hmat, a_l, a_r);
}

// standalone prep (non-fused workspace tier)
__global__ void __launch_bounds__(256) k_prep(const void* __restrict__ xin,
                                              const void* __restrict__ W,
                                              const void* __restrict__ att,
                                              const int* __restrict__ flags,
                                              unsigned char* __restrict__ fhat,
                                              __hip_bfloat16* __restrict__ Hmat,
                                              float* __restrict__ a_l,
                                              float* __restrict__ a_r, int N) {
  const int lane = threadIdx.x & 63;
  const int wid = (blockIdx.x * 256 + threadIdx.x) >> 6;
  if (wid >= N) return;
  const int f32 = flags[0];
  float f = ldv(xin, (size_t)wid * D + lane, f32);
  prep_node(f, f32, wid, lane, W, att, fhat, Hmat, a_l, a_r);
}

// ---------------- edge kernel: wave per dst node, 8-edge/8-lane groups ----------------
__global__ void __launch_bounds__(256) k_edge(const int* __restrict__ cnt,
                                              const unsigned int* __restrict__ csr2,
                                              const int* __restrict__ ei,
                                              const void* __restrict__ w,
                                              const unsigned char* __restrict__ fhat,
                                              const __hip_bfloat16* __restrict__ Hmat,
                                              const float* __restrict__ a_l,
                                              const float* __restrict__ a_r,
                                              const void* __restrict__ beta,
                                              const void* __restrict__ bias,
                                              const void* __restrict__ x,
                                              const void* __restrict__ rW1,
                                              const void* __restrict__ rb1,
                                              const void* __restrict__ rW2,
                                              const void* __restrict__ rb2,
                                              const void* __restrict__ Wn,
                                              const void* __restrict__ attn,
                                              unsigned char* __restrict__ fh2,
                                              __hip_bfloat16* __restrict__ Hm2,
                                              float* __restrict__ al2,
                                              float* __restrict__ ar2,
                                              const int* __restrict__ flags,
                                              void* __restrict__ out,
                                              int N, int E, int mode) {
  const int lane = threadIdx.x & 63;
  const int wv = threadIdx.x >> 6;
  const int wid = blockIdx.x * 4 + wv;
  __shared__ float2 lds_lc[4][CAP];  // (l, c)
  __shared__ float2 lds_sg[4][CAP];  // (packed bits, -) -> later (src bits, p)
  __shared__ float lds_t[4][D];
  if (wid >= N) return;
  const int f32 = flags[0];
  const int g = lane >> 3;   // edge slot in 8-edge group
  const int sub = lane & 7;  // feature block: [8*sub, 8*sub+8)
  const int degRaw = cnt[wid];
  const float aln = a_l[wid];
  const float bb = 1.f / (1.f + __expf(-ldv(beta, 0, f32)));
  const float ob = 1.f - bb;
  float2* lc = lds_lc[wv];
  float2* sg = lds_sg[wv];

  float v;  // pre-elu output feature for this lane
  if (degRaw <= CAP) {
    // ================= fast path (always taken on bench data) =================
    const int deg = degRaw;
    const int s = wid * CAP;
    float fn[8];
    dec_fp8x8(((const uint2*)(fhat + (size_t)wid * D))[sub], fn);

    // ---- phase 1: 8 edges/iter (unroll 4); fp8 64B row gathers ----
    float m1 = -1e30f, m2 = -1e30f;
#pragma unroll 4
    for (int base = 0; base < deg; base += 8) {
      const int j = base + g;
      const bool val = j < deg;
      const unsigned int en = val ? csr2[s + j] : (unsigned int)wid;
      const int src = upk_src(en, N);
      float hv[8];
      dec_fp8x8(((const uint2*)(fhat + (size_t)src * D))[sub], hv);
      float d = 0.f;
#pragma unroll
      for (int i = 0; i < 8; ++i) d += fn[i] * hv[i];
      d += __shfl_xor(d, 1, 64);
      d += __shfl_xor(d, 2, 64);
      d += __shfl_xor(d, 4, 64);
      float l = aln + a_r[src];
      l = (l >= 0.f) ? l : NEG_SLOPE * l;
      if (val) {
        m1 = fmaxf(m1, l);
        m2 = fmaxf(m2, d);
        if (sub == 0) {
          lc[j] = make_float2(l, d);
          sg[j] = make_float2(__uint_as_float(en), 0.f);
        }
      }
    }
    m1 = fmaxf(m1, __shfl_xor(m1, 8, 64));
    m1 = fmaxf(m1, __shfl_xor(m1, 16, 64));
    m1 = fmaxf(m1, __shfl_xor(m1, 32, 64));
    m2 = fmaxf(m2, __shfl_xor(m2, 8, 64));
    m2 = fmaxf(m2, __shfl_xor(m2, 16, 64));
    m2 = fmaxf(m2, __shfl_xor(m2, 32, 64));

    // ---- phase 2: dual softmax sums + fused p (deg <= 64 always) ----
    float el0 = 0.f, ec0 = 0.f, gg0 = 0.f;
    int q0 = 0;
    float ps1 = 0.f, ps2 = 0.f;
    if (lane < deg) {
      unsigned int en = __float_as_uint(sg[lane].x);
      q0 = upk_src(en, N);
      gg0 = upk_gate(en);
      float2 t = lc[lane];
      el0 = __expf(t.x - m1);
      ec0 = __expf(t.y - m2);
      ps1 += el0;
      ps2 += ec0;
    }
    const float rs1 = 1.f / (wred_sum(ps1) + EPS_SM);
    const float rs2 = 1.f / (wred_sum(ps2) + EPS_SM);

    float sp = 0.f;
    if (lane < deg) {
      float tt = (ob * el0 * rs1 + bb * ec0 * rs2) * gg0;
      float p0 = __expf(tt - 1.f);
      sp += p0;
      sg[lane] = make_float2(__int_as_float(q0), p0);  // (src, p)
    }
    const float rinv = 1.f / (wred_sum(sp) + EPS_SM);

    // ---- phase 3: (src,p) broadcast from LDS, Hmat row gathers ----
    float acc[8] = {0.f, 0.f, 0.f, 0.f, 0.f, 0.f, 0.f, 0.f};
#pragma unroll 4
    for (int base = 0; base < deg; base += 8) {
      const int j = base + g;
      float2 en = (j < deg) ? sg[j] : make_float2(__int_as_float(wid), 0.f);
      const float pv = en.y;
      const int srcv = __float_as_int(en.x);
      float hv[8];
      unp8(((const uint4*)(Hmat + (size_t)srcv * D))[sub], hv);
#pragma unroll
      for (int i = 0; i < 8; ++i) acc[i] += pv * hv[i];
    }
#pragma unroll
    for (int i = 0; i < 8; ++i) {
      acc[i] += __shfl_xor(acc[i], 8, 64);
      acc[i] += __shfl_xor(acc[i], 16, 64);
      acc[i] += __shfl_xor(acc[i], 32, 64);
    }
    if (g == 0) {
#pragma unroll
      for (int i = 0; i < 8; ++i) lds_t[wv][8 * sub + i] = acc[i];
    }
    v = lds_t[wv][lane] * rinv + ldv(bias, lane, f32);
  } else {
    // ============ slow path: exact 3-pass over raw edge list ============
    // (deg > CAP; probability ~1e-10 on Poisson(25.6) data — correctness only)
    const int wide = flags[1];
    lds_t[wv][lane] = 0.f;
    float m1 = -1e30f, m2 = -1e30f;
    for (int e64 = lane; e64 < E; e64 += 64) {
      int dd = wide ? ei[2 * (size_t)E + 2 * (size_t)e64] : ei[(size_t)E + e64];
      if (dd != wid) continue;
      int ss = wide ? ei[2 * (size_t)e64] : ei[e64];
      ss = min(max(ss, 0), N - 1);
      float l = aln + a_r[ss];
      l = (l >= 0.f) ? l : NEG_SLOPE * l;
      float c = slow_cos(fhat, wid, ss);
      m1 = fmaxf(m1, l);
      m2 = fmaxf(m2, c);
    }
    m1 = wred_max(m1);
    m2 = wred_max(m2);
    float ps1 = 0.f, ps2 = 0.f;
    for (int e64 = lane; e64 < E; e64 += 64) {
      int dd = wide ? ei[2 * (size_t)E + 2 * (size_t)e64] : ei[(size_t)E + e64];
      if (dd != wid) continue;
      int ss = wide ? ei[2 * (size_t)e64] : ei[e64];
      ss = min(max(ss, 0), N - 1);
      float l = aln + a_r[ss];
      l = (l >= 0.f) ? l : NEG_SLOPE * l;
      float c = slow_cos(fhat, wid, ss);
      ps1 += __expf(l - m1);
      ps2 += __expf(c - m2);
    }
    const float rs1 = 1.f / (wred_sum(ps1) + EPS_SM);
    const float rs2 = 1.f / (wred_sum(ps2) + EPS_SM);
    float sp = 0.f;
    for (int e64 = lane; e64 < E; e64 += 64) {
      int dd = wide ? ei[2 * (size_t)E + 2 * (size_t)e64] : ei[(size_t)E + e64];
      if (dd != wid) continue;
      int ss = wide ? ei[2 * (size_t)e64] : ei[e64];
      ss = min(max(ss, 0), N - 1);
      float l = aln + a_r[ss];
      l = (l >= 0.f) ? l : NEG_SLOPE * l;
      float c = slow_cos(fhat, wid, ss);
      float gx = gate_of(ldv(w, e64, f32));
      float px = __expf((ob * __expf(l - m1) * rs1 + bb * __expf(c - m2) * rs2) * gx - 1.f);
      sp += px;
      for (int q = 0; q < D; ++q)
        atomicAdd(&lds_t[wv][q], px * __bfloat162float(Hmat[(size_t)ss * D + q]));
    }
    const float rinv = 1.f / (wred_sum(sp) + EPS_SM);
    v = lds_t[wv][lane] * rinv + ldv(bias, lane, f32);
  }

  v = elu1(v);  // elu inside _cosgat
  if (mode == 1) {
    // fused residual MLP: relu(x@rW1+rb1)@rW2+rb2 (4-chain ILP)
    float xv = ldv(x, (size_t)wid * D + lane, f32);
    float a2;
    float b0_ = ldv(rb1, lane, f32);
    float h0 = 0.f, h1 = 0.f, h2 = 0.f, h3 = 0.f;
    if (f32) {
      const float* w1 = (const float*)rW1;
      const float* w2 = (const float*)rW2;
#pragma unroll 4
      for (int k = 0; k < D; k += 4) {
        h0 += __shfl(xv, k, 64) * w1[k * D + lane];
        h1 += __shfl(xv, k + 1, 64) * w1[(k + 1) * D + lane];
        h2 += __shfl(xv, k + 2, 64) * w1[(k + 2) * D + lane];
        h3 += __shfl(xv, k + 3, 64) * w1[(k + 3) * D + lane];
      }
      float tr = fmaxf(b0_ + (h0 + h1) + (h2 + h3), 0.f);
      float g0 = 0.f, g1 = 0.f, g2 = 0.f, g3 = 0.f;
#pragma unroll 4
      for (int k = 0; k < D; k += 4) {
        g0 += __shfl(tr, k, 64) * w2[k * D + lane];
        g1 += __shfl(tr, k + 1, 64) * w2[(k + 1) * D + lane];
        g2 += __shfl(tr, k + 2, 64) * w2[(k + 2) * D + lane];
        g3 += __shfl(tr, k + 3, 64) * w2[(k + 3) * D + lane];
      }
      a2 = ((const float*)rb2)[lane] + (g0 + g1) + (g2 + g3);
    } else {
      const __hip_bfloat16* w1 = (const __hip_bfloat16*)rW1;
      const __hip_bfloat16* w2 = (const __hip_bfloat16*)rW2;
#pragma unroll 4
      for (int k = 0; k < D; k += 4) {
        h0 += __shfl(xv, k, 64) * __bfloat162float(w1[k * D + lane]);
        h1 += __shfl(xv, k + 1, 64) * __bfloat162float(w1[(k + 1) * D + lane]);
        h2 += __shfl(xv, k + 2, 64) * __bfloat162float(w1[(k + 2) * D + lane]);
        h3 += __shfl(xv, k + 3, 64) * __bfloat162float(w1[(k + 3) * D + lane]);
      }
      float tr = fmaxf(b0_ + (h0 + h1) + (h2 + h3), 0.f);
      float g0 = 0.f, g1 = 0.f, g2 = 0.f, g3 = 0.f;
#pragma unroll 4
      for (int k = 0; k < D; k += 4) {
        g0 += __shfl(tr, k, 64) * __bfloat162float(w2[k * D + lane]);
        g1 += __shfl(tr, k + 1, 64) * __bfloat162float(w2[(k + 1) * D + lane]);
        g2 += __shfl(tr, k + 2, 64) * __bfloat162float(w2[(k + 2) * D + lane]);
        g3 += __shfl(tr, k + 3, 64) * __bfloat162float(w2[(k + 3) * D + lane]);
      }
      a2 = __bfloat162float(((const __hip_bfloat16*)rb2)[lane]) + (g0 + g1) + (g2 + g3);
    }
    stv(out, (size_t)wid * D + lane, f32, sane(v + a2));
  } else {
    v = elu1(v);  // inter-layer elu
    if (mode == 0) {
      prep_node(sane(v), f32, wid, lane, Wn, attn, fh2, Hm2, al2, ar2);
    } else {
      stv(out, (size_t)wid * D + lane, f32, sane(v));
    }
  }
}

extern "C" void kernel_launch(void* const* d_in, const int* in_sizes, int n_in,
                              void* d_out, int out_size, void* d_ws, size_t ws_size,
                              hipStream_t stream) {
  const void* x = d_in[0];
  const int* ei = (const int*)d_in[1];
  const void* w = d_in[2];
  const void* W0 = d_in[3];
  const void* att0 = d_in[4];
  const void* beta0 = d_in[5];
  const void* b0 = d_in[6];
  const void* W1 = d_in[7];
  const void* att1 = d_in[8];
  const void* beta1 = d_in[9];
  const void* b1 = d_in[10];
  const void* rW1 = d_in[11];
  const void* rb1 = d_in[12];
  const void* rW2 = d_in[13];
  const void* rb2 = d_in[14];

  const int N = in_sizes[0] / D;
  const int E = in_sizes[2];

  char* base = (char*)d_ws;
  size_t off = 0;
  auto alloc = [&](size_t bytes) -> void* {
    void* p = base + off;
    off += (bytes + 255) & ~(size_t)255;
    return p;
  };
  // always-needed tier
  int* flags = (int*)alloc(256);
  int* cnt = (int*)alloc((size_t)N * 4);
  unsigned int* csr2 = (unsigned int*)alloc((size_t)N * CAP * 4);
  unsigned char* fhat = (unsigned char*)alloc((size_t)N * D);
  __hip_bfloat16* Hmat = (__hip_bfloat16*)alloc((size_t)N * D * 2);
  float* a_l = (float*)alloc((size_t)N * 4);
  float* a_r = (float*)alloc((size_t)N * 4);
  // fused tier (second-layer prep buffers)
  unsigned char* fhat2 = (unsigned char*)alloc((size_t)N * D);
  __hip_bfloat16* Hmat2 = (__hip_bfloat16*)alloc((size_t)N * D * 2);
  float* a_l2 = (float*)alloc((size_t)N * 4);
  float* a_r2 = (float*)alloc((size_t)N * 4);
  const bool fused = (off <= ws_size);

  const int nb = (N + 3) / 4;

  hipMemsetAsync(cnt, 0, (size_t)N * 4, stream);
  k_all<<<nb, 256, 0, stream>>>((const unsigned short*)x, ei, w, flags, cnt,
                                x, W0, att0, fhat, Hmat, a_l, a_r, csr2, N, E);

  if (fused) {
    k_edge<<<nb, 256, 0, stream>>>(cnt, csr2, ei, w, fhat, Hmat, a_l, a_r,
                                   beta0, b0, x, rW1, rb1, rW2, rb2,
                                   W1, att1, fhat2, Hmat2, a_l2, a_r2,
                                   flags, d_out, N, E, 0);
    k_edge<<<nb, 256, 0, stream>>>(cnt, csr2, ei, w, fhat2, Hmat2, a_l2, a_r2,
                                   beta1, b1, x, rW1, rb1, rW2, rb2,
                                   nullptr, nullptr, nullptr, nullptr, nullptr, nullptr,
                                   flags, d_out, N, E, 1);
  } else {
    k_edge<<<nb, 256, 0, stream>>>(cnt, csr2, ei, w, fhat, Hmat, a_l, a_r,
                                   beta0, b0, x, rW1, rb1, rW2, rb2,
                                   nullptr, nullptr, nullptr, nullptr, nullptr, nullptr,
                                   flags, d_out, N, E, 2);
    k_prep<<<nb, 256, 0, stream>>>(d_out, W1, att1, flags, fhat, Hmat, a_l, a_r, N);
    k_edge<<<nb, 256, 0, stream>>>(cnt, csr2, ei, w, fhat, Hmat, a_l, a_r,
                                   beta1, b1, x, rW1, rb1, rW2, rb2,
                                   nullptr, nullptr, nullptr, nullptr, nullptr, nullptr,
                                   flags, d_out, N, E, 1);
  }
}

// Round 4
// 408.863 us; speedup vs baseline: 1.2705x; 1.1005x over previous
//
#include <hip/hip_runtime.h>
#include <hip/hip_bf16.h>
#include <math.h>

// COSGATEncoder: N=50000, E=1280000, D=64, HEADS=1. f32 in/out (runtime-detected,
// bf16 fallback), edge_index int64 (runtime-detected, int32 fallback).
// R16: k_edge goes 1-wave-per-block (64 threads, grid=N). R15 showed achieved
// occupancy 50% with 256-thread blocks: 4 unequal-lifetime waves (Poisson degree
// + mode-0 prep epilogue) retire as one unit, fragmenting wave slots. 64-thread
// blocks release slots per-wave; LDS 1.28KB/block -> static ceiling 32 waves/CU.
// launch_bounds(64,8) caps VGPR at 64 (currently 44, no pressure).
// Rest = R15: slot-CSR (memset, k_all, k_edge x2 = 4 dispatches), exact slow
// path for deg>CAP, 4-chain ILP in prep/MLP, fp8 fhat rows, packed 4B csr.

constexpr int D = 64;
constexpr int CAP = 64;
constexpr float NEG_SLOPE = 0.2f;
constexpr float EPS_COS = 1e-8f;
constexpr float EPS_SM = 1e-16f;

#if defined(__has_builtin)
#if __has_builtin(__builtin_amdgcn_cvt_pk_f32_fp8) && __has_builtin(__builtin_amdgcn_cvt_pk_fp8_f32)
#define HW_FP8 1
#endif
#endif

typedef float floatx2 __attribute__((ext_vector_type(2)));

__device__ __forceinline__ float wred_sum(float v) {
#pragma unroll
  for (int off = 32; off > 0; off >>= 1) v += __shfl_xor(v, off, 64);
  return v;
}
__device__ __forceinline__ float wred_max(float v) {
#pragma unroll
  for (int off = 32; off > 0; off >>= 1) v = fmaxf(v, __shfl_xor(v, off, 64));
  return v;
}
__device__ __forceinline__ float elu1(float x) { return x > 0.f ? x : __expf(x) - 1.f; }
__device__ __forceinline__ float sane(float v) {
  return (v == v && fabsf(v) < 1e30f) ? v : 0.f;
}
__device__ __forceinline__ float ldv(const void* p, size_t i, int f32) {
  return f32 ? ((const float*)p)[i]
             : __bfloat162float(((const __hip_bfloat16*)p)[i]);
}
__device__ __forceinline__ void stv(void* p, size_t i, int f32, float v) {
  if (f32) ((float*)p)[i] = v;
  else ((__hip_bfloat16*)p)[i] = __float2bfloat16(v);
}
__device__ __forceinline__ float b2f(unsigned short u) {
  return __uint_as_float(((unsigned int)u) << 16);
}
__device__ __forceinline__ void unp8(uint4 u, float* f) {
  f[0] = __uint_as_float(u.x << 16);
  f[1] = __uint_as_float(u.x & 0xffff0000u);
  f[2] = __uint_as_float(u.y << 16);
  f[3] = __uint_as_float(u.y & 0xffff0000u);
  f[4] = __uint_as_float(u.z << 16);
  f[5] = __uint_as_float(u.z & 0xffff0000u);
  f[6] = __uint_as_float(u.w << 16);
  f[7] = __uint_as_float(u.w & 0xffff0000u);
}

// ---- fp8 helpers: HW e4m3 when available, f16-msb (e5m2-like) fallback ----
__device__ __forceinline__ unsigned char enc_fp8(float v) {
#ifdef HW_FP8
  int pk = __builtin_amdgcn_cvt_pk_fp8_f32(v, v, 0, false);
  return (unsigned char)(pk & 0xFF);
#else
  _Float16 h = (_Float16)v;
  unsigned short ub;
  __builtin_memcpy(&ub, &h, 2);
  return (unsigned char)((ub + 0x80) >> 8);  // RNE-ish truncate to top byte
#endif
}
__device__ __forceinline__ void dec_fp8x8(uint2 u, float* f) {
#ifdef HW_FP8
  floatx2 a = __builtin_amdgcn_cvt_pk_f32_fp8(u.x, false);
  floatx2 b = __builtin_amdgcn_cvt_pk_f32_fp8(u.x, true);
  floatx2 c = __builtin_amdgcn_cvt_pk_f32_fp8(u.y, false);
  floatx2 d = __builtin_amdgcn_cvt_pk_f32_fp8(u.y, true);
  f[0] = a[0]; f[1] = a[1]; f[2] = b[0]; f[3] = b[1];
  f[4] = c[0]; f[5] = c[1]; f[6] = d[0]; f[7] = d[1];
#else
#pragma unroll
  for (int i = 0; i < 8; ++i) {
    unsigned int byte = (i < 4 ? (u.x >> (8 * i)) : (u.y >> (8 * (i - 4)))) & 0xFF;
    unsigned short hb = (unsigned short)(byte << 8);
    _Float16 h;
    __builtin_memcpy(&h, &hb, 2);
    f[i] = (float)h;
  }
#endif
}

// packed csr entry: bits 0..17 = src, bits 18..31 = gate quantized to 14 bits
__device__ __forceinline__ unsigned int pack_sg(int src, float g) {
  int gq = (int)(g * 16383.f + 0.5f);
  return ((unsigned int)src & 0x3FFFFu) | ((unsigned int)gq << 18);
}
__device__ __forceinline__ int upk_src(unsigned int e, int N) {
  return min((int)(e & 0x3FFFFu), N - 1);
}
__device__ __forceinline__ float upk_gate(unsigned int e) {
  return (float)(e >> 18) * (1.f / 16383.f);
}
__device__ __forceinline__ float gate_of(float w) {
  return fminf(fmaxf(1.f - 0.25f * fminf(w, 4.f), 0.f), 1.f);
}

// full fp8-row cosine dot (slow path only)
__device__ float slow_cos(const unsigned char* __restrict__ fhat, int a, int b) {
  const uint2* fa = (const uint2*)(fhat + (size_t)a * D);
  const uint2* fb = (const uint2*)(fhat + (size_t)b * D);
  float dsum = 0.f;
  for (int q = 0; q < 8; ++q) {
    float va[8], vb[8];
    dec_fp8x8(fa[q], va);
    dec_fp8x8(fb[q], vb);
#pragma unroll
    for (int i = 0; i < 8; ++i) dsum += va[i] * vb[i];
  }
  return dsum;
}

// shared prep body: node features (lane=feature) -> fhat(fp8), Hmat(bf16), a_l, a_r
__device__ __forceinline__ void prep_node(float f, int f32, int wid, int lane,
                                          const void* __restrict__ W,
                                          const void* __restrict__ att,
                                          unsigned char* __restrict__ fhat,
                                          __hip_bfloat16* __restrict__ Hmat,
                                          float* __restrict__ a_l,
                                          float* __restrict__ a_r) {
  float n2 = wred_sum(f * f);
  float nrm = fmaxf(sqrtf(n2), EPS_COS);
  fhat[(size_t)wid * D + lane] = enc_fp8(f / nrm);
  // 4 independent accumulator chains (dependent-FMA latency / 4)
  float h0 = 0.f, h1 = 0.f, h2 = 0.f, h3 = 0.f;
  if (f32) {
    const float* Wf = (const float*)W;
#pragma unroll 4
    for (int k = 0; k < D; k += 4) {
      h0 += __shfl(f, k, 64) * Wf[k * D + lane];
      h1 += __shfl(f, k + 1, 64) * Wf[(k + 1) * D + lane];
      h2 += __shfl(f, k + 2, 64) * Wf[(k + 2) * D + lane];
      h3 += __shfl(f, k + 3, 64) * Wf[(k + 3) * D + lane];
    }
  } else {
    const __hip_bfloat16* Wb = (const __hip_bfloat16*)W;
#pragma unroll 4
    for (int k = 0; k < D; k += 4) {
      h0 += __shfl(f, k, 64) * __bfloat162float(Wb[k * D + lane]);
      h1 += __shfl(f, k + 1, 64) * __bfloat162float(Wb[(k + 1) * D + lane]);
      h2 += __shfl(f, k + 2, 64) * __bfloat162float(Wb[(k + 2) * D + lane]);
      h3 += __shfl(f, k + 3, 64) * __bfloat162float(Wb[(k + 3) * D + lane]);
    }
  }
  float Hc = (h0 + h1) + (h2 + h3);
  Hmat[(size_t)wid * D + lane] = __float2bfloat16(Hc);
  float al = wred_sum(Hc * ldv(att, lane, f32));
  float ar = wred_sum(Hc * ldv(att, D + lane, f32));
  if (lane == 0) {
    a_l[wid] = al;
    a_r[wid] = ar;
  }
}

// fused: dtype detect + layer-0 prep + slot-CSR edge placement (one kernel)
__global__ void __launch_bounds__(256) k_all(const unsigned short* __restrict__ xu,
                                             const int* __restrict__ ei,
                                             const void* __restrict__ w,
                                             int* __restrict__ flags,
                                             int* __restrict__ cnt,
                                             const void* __restrict__ x,
                                             const void* __restrict__ W,
                                             const void* __restrict__ att,
                                             unsigned char* __restrict__ fhat,
                                             __hip_bfloat16* __restrict__ Hmat,
                                             float* __restrict__ a_l,
                                             float* __restrict__ a_r,
                                             unsigned int* __restrict__ csr2,
                                             int N, int E) {
  __shared__ int sf[2];
  const int tid = threadIdx.x;
  if (tid < 64) {
    float v = b2f(xu[tid]);
    float a = fabsf(v);
    unsigned long long m = __ballot(a > 1e-4f && a < 100.f);
    unsigned long long m2 = __ballot(ei[2 * tid + 1] != 0);
    if (tid == 0) {
      sf[0] = (__popcll(m) >= 60) ? 0 : 1;  // 1 => f32
      sf[1] = (m2 == 0ull) ? 1 : 0;         // 1 => int64
      if (blockIdx.x == 0) {
        flags[0] = sf[0];
        flags[1] = sf[1];
      }
    }
  }
  __syncthreads();
  const int f32 = sf[0], wide = sf[1];
  // ---- edge placement: 2 edges/thread, slot via atomicAdd on cnt[dst] ----
  {
    const int e0 = (blockIdx.x * 256 + tid) * 2;
    if (e0 < E) {
      const bool has1 = (e0 + 1 < E);
      int s0, s1, d0, d1;
      if (wide) {
        int4 vs = *(const int4*)(ei + 2 * (size_t)e0);
        int4 vd = *(const int4*)(ei + 2 * (size_t)E + 2 * (size_t)e0);
        s0 = vs.x; s1 = vs.z; d0 = vd.x; d1 = vd.z;
      } else {
        int2 vs = *(const int2*)(ei + e0);
        int2 vd = *(const int2*)(ei + (size_t)E + e0);
        s0 = vs.x; s1 = vs.y; d0 = vd.x; d1 = vd.y;
      }
      float w0, w1 = 0.f;
      if (f32) {
        float2 wv = *(const float2*)((const float*)w + e0);
        w0 = wv.x; w1 = wv.y;
      } else {
        const __hip_bfloat16* wb = (const __hip_bfloat16*)w;
        w0 = __bfloat162float(wb[e0]);
        if (has1) w1 = __bfloat162float(wb[e0 + 1]);
      }
      int d0c = min(max(d0, 0), N - 1);
      int slot0 = atomicAdd(&cnt[d0c], 1);
      if (slot0 < CAP) csr2[(size_t)d0c * CAP + slot0] = pack_sg(min(max(s0, 0), N - 1), gate_of(w0));
      if (has1) {
        int d1c = min(max(d1, 0), N - 1);
        int slot1 = atomicAdd(&cnt[d1c], 1);
        if (slot1 < CAP) csr2[(size_t)d1c * CAP + slot1] = pack_sg(min(max(s1, 0), N - 1), gate_of(w1));
      }
    }
  }
  // ---- node prep: wave per node ----
  const int lane = tid & 63;
  const int wid = blockIdx.x * 4 + (tid >> 6);
  if (wid >= N) return;
  float f = ldv(x, (size_t)wid * D + lane, f32);
  prep_node(f, f32, wid, lane, W, att, fhat, Hmat, a_l, a_r);
}

// standalone prep (non-fused workspace tier)
__global__ void __launch_bounds__(256) k_prep(const void* __restrict__ xin,
                                              const void* __restrict__ W,
                                              const void* __restrict__ att,
                                              const int* __restrict__ flags,
                                              unsigned char* __restrict__ fhat,
                                              __hip_bfloat16* __restrict__ Hmat,
                                              float* __restrict__ a_l,
                                              float* __restrict__ a_r, int N) {
  const int lane = threadIdx.x & 63;
  const int wid = (blockIdx.x * 256 + threadIdx.x) >> 6;
  if (wid >= N) return;
  const int f32 = flags[0];
  float f = ldv(xin, (size_t)wid * D + lane, f32);
  prep_node(f, f32, wid, lane, W, att, fhat, Hmat, a_l, a_r);
}

// ---------------- edge kernel: ONE wave per dst node (64-thread blocks) ----------------
__global__ void __launch_bounds__(64, 8) k_edge(const int* __restrict__ cnt,
                                                const unsigned int* __restrict__ csr2,
                                                const int* __restrict__ ei,
                                                const void* __restrict__ w,
                                                const unsigned char* __restrict__ fhat,
                                                const __hip_bfloat16* __restrict__ Hmat,
                                                const float* __restrict__ a_l,
                                                const float* __restrict__ a_r,
                                                const void* __restrict__ beta,
                                                const void* __restrict__ bias,
                                                const void* __restrict__ x,
                                                const void* __restrict__ rW1,
                                                const void* __restrict__ rb1,
                                                const void* __restrict__ rW2,
                                                const void* __restrict__ rb2,
                                                const void* __restrict__ Wn,
                                                const void* __restrict__ attn,
                                                unsigned char* __restrict__ fh2,
                                                __hip_bfloat16* __restrict__ Hm2,
                                                float* __restrict__ al2,
                                                float* __restrict__ ar2,
                                                const int* __restrict__ flags,
                                                void* __restrict__ out,
                                                int N, int E, int mode) {
  const int lane = threadIdx.x;
  const int wid = blockIdx.x;
  __shared__ float2 lc[CAP];  // (l, c)
  __shared__ float2 sg[CAP];  // (packed bits, -) -> later (src bits, p)
  __shared__ float lds_t[D];
  if (wid >= N) return;
  const int f32 = flags[0];
  const int g = lane >> 3;   // edge slot in 8-edge group
  const int sub = lane & 7;  // feature block: [8*sub, 8*sub+8)
  const int degRaw = cnt[wid];
  const float aln = a_l[wid];
  const float bb = 1.f / (1.f + __expf(-ldv(beta, 0, f32)));
  const float ob = 1.f - bb;

  float v;  // pre-elu output feature for this lane
  if (degRaw <= CAP) {
    // ================= fast path (always taken on bench data) =================
    const int deg = degRaw;
    const int s = wid * CAP;
    float fn[8];
    dec_fp8x8(((const uint2*)(fhat + (size_t)wid * D))[sub], fn);

    // ---- phase 1: 8 edges/iter (unroll 4); fp8 64B row gathers ----
    float m1 = -1e30f, m2 = -1e30f;
#pragma unroll 4
    for (int base = 0; base < deg; base += 8) {
      const int j = base + g;
      const bool val = j < deg;
      const unsigned int en = val ? csr2[s + j] : (unsigned int)wid;
      const int src = upk_src(en, N);
      float hv[8];
      dec_fp8x8(((const uint2*)(fhat + (size_t)src * D))[sub], hv);
      float d = 0.f;
#pragma unroll
      for (int i = 0; i < 8; ++i) d += fn[i] * hv[i];
      d += __shfl_xor(d, 1, 64);
      d += __shfl_xor(d, 2, 64);
      d += __shfl_xor(d, 4, 64);
      float l = aln + a_r[src];
      l = (l >= 0.f) ? l : NEG_SLOPE * l;
      if (val) {
        m1 = fmaxf(m1, l);
        m2 = fmaxf(m2, d);
        if (sub == 0) {
          lc[j] = make_float2(l, d);
          sg[j] = make_float2(__uint_as_float(en), 0.f);
        }
      }
    }
    m1 = fmaxf(m1, __shfl_xor(m1, 8, 64));
    m1 = fmaxf(m1, __shfl_xor(m1, 16, 64));
    m1 = fmaxf(m1, __shfl_xor(m1, 32, 64));
    m2 = fmaxf(m2, __shfl_xor(m2, 8, 64));
    m2 = fmaxf(m2, __shfl_xor(m2, 16, 64));
    m2 = fmaxf(m2, __shfl_xor(m2, 32, 64));

    // ---- phase 2: dual softmax sums + fused p (deg <= 64 always) ----
    float el0 = 0.f, ec0 = 0.f, gg0 = 0.f;
    int q0 = 0;
    float ps1 = 0.f, ps2 = 0.f;
    if (lane < deg) {
      unsigned int en = __float_as_uint(sg[lane].x);
      q0 = upk_src(en, N);
      gg0 = upk_gate(en);
      float2 t = lc[lane];
      el0 = __expf(t.x - m1);
      ec0 = __expf(t.y - m2);
      ps1 += el0;
      ps2 += ec0;
    }
    const float rs1 = 1.f / (wred_sum(ps1) + EPS_SM);
    const float rs2 = 1.f / (wred_sum(ps2) + EPS_SM);

    float sp = 0.f;
    if (lane < deg) {
      float tt = (ob * el0 * rs1 + bb * ec0 * rs2) * gg0;
      float p0 = __expf(tt - 1.f);
      sp += p0;
      sg[lane] = make_float2(__int_as_float(q0), p0);  // (src, p)
    }
    const float rinv = 1.f / (wred_sum(sp) + EPS_SM);

    // ---- phase 3: (src,p) broadcast from LDS, Hmat row gathers ----
    float acc[8] = {0.f, 0.f, 0.f, 0.f, 0.f, 0.f, 0.f, 0.f};
#pragma unroll 4
    for (int base = 0; base < deg; base += 8) {
      const int j = base + g;
      float2 en = (j < deg) ? sg[j] : make_float2(__int_as_float(wid), 0.f);
      const float pv = en.y;
      const int srcv = __float_as_int(en.x);
      float hv[8];
      unp8(((const uint4*)(Hmat + (size_t)srcv * D))[sub], hv);
#pragma unroll
      for (int i = 0; i < 8; ++i) acc[i] += pv * hv[i];
    }
#pragma unroll
    for (int i = 0; i < 8; ++i) {
      acc[i] += __shfl_xor(acc[i], 8, 64);
      acc[i] += __shfl_xor(acc[i], 16, 64);
      acc[i] += __shfl_xor(acc[i], 32, 64);
    }
    if (g == 0) {
#pragma unroll
      for (int i = 0; i < 8; ++i) lds_t[8 * sub + i] = acc[i];
    }
    v = lds_t[lane] * rinv + ldv(bias, lane, f32);
  } else {
    // ============ slow path: exact 3-pass over raw edge list ============
    // (deg > CAP; probability ~1e-10 on Poisson(25.6) data — correctness only)
    const int wide = flags[1];
    lds_t[lane] = 0.f;
    float m1 = -1e30f, m2 = -1e30f;
    for (int e64 = lane; e64 < E; e64 += 64) {
      int dd = wide ? ei[2 * (size_t)E + 2 * (size_t)e64] : ei[(size_t)E + e64];
      if (dd != wid) continue;
      int ss = wide ? ei[2 * (size_t)e64] : ei[e64];
      ss = min(max(ss, 0), N - 1);
      float l = aln + a_r[ss];
      l = (l >= 0.f) ? l : NEG_SLOPE * l;
      float c = slow_cos(fhat, wid, ss);
      m1 = fmaxf(m1, l);
      m2 = fmaxf(m2, c);
    }
    m1 = wred_max(m1);
    m2 = wred_max(m2);
    float ps1 = 0.f, ps2 = 0.f;
    for (int e64 = lane; e64 < E; e64 += 64) {
      int dd = wide ? ei[2 * (size_t)E + 2 * (size_t)e64] : ei[(size_t)E + e64];
      if (dd != wid) continue;
      int ss = wide ? ei[2 * (size_t)e64] : ei[e64];
      ss = min(max(ss, 0), N - 1);
      float l = aln + a_r[ss];
      l = (l >= 0.f) ? l : NEG_SLOPE * l;
      float c = slow_cos(fhat, wid, ss);
      ps1 += __expf(l - m1);
      ps2 += __expf(c - m2);
    }
    const float rs1 = 1.f / (wred_sum(ps1) + EPS_SM);
    const float rs2 = 1.f / (wred_sum(ps2) + EPS_SM);
    float sp = 0.f;
    for (int e64 = lane; e64 < E; e64 += 64) {
      int dd = wide ? ei[2 * (size_t)E + 2 * (size_t)e64] : ei[(size_t)E + e64];
      if (dd != wid) continue;
      int ss = wide ? ei[2 * (size_t)e64] : ei[e64];
      ss = min(max(ss, 0), N - 1);
      float l = aln + a_r[ss];
      l = (l >= 0.f) ? l : NEG_SLOPE * l;
      float c = slow_cos(fhat, wid, ss);
      float gx = gate_of(ldv(w, e64, f32));
      float px = __expf((ob * __expf(l - m1) * rs1 + bb * __expf(c - m2) * rs2) * gx - 1.f);
      sp += px;
      for (int q = 0; q < D; ++q)
        atomicAdd(&lds_t[q], px * __bfloat162float(Hmat[(size_t)ss * D + q]));
    }
    const float rinv = 1.f / (wred_sum(sp) + EPS_SM);
    v = lds_t[lane] * rinv + ldv(bias, lane, f32);
  }

  v = elu1(v);  // elu inside _cosgat
  if (mode == 1) {
    // fused residual MLP: relu(x@rW1+rb1)@rW2+rb2 (4-chain ILP)
    float xv = ldv(x, (size_t)wid * D + lane, f32);
    float a2;
    float b0_ = ldv(rb1, lane, f32);
    float h0 = 0.f, h1 = 0.f, h2 = 0.f, h3 = 0.f;
    if (f32) {
      const float* w1 = (const float*)rW1;
      const float* w2 = (const float*)rW2;
#pragma unroll 4
      for (int k = 0; k < D; k += 4) {
        h0 += __shfl(xv, k, 64) * w1[k * D + lane];
        h1 += __shfl(xv, k + 1, 64) * w1[(k + 1) * D + lane];
        h2 += __shfl(xv, k + 2, 64) * w1[(k + 2) * D + lane];
        h3 += __shfl(xv, k + 3, 64) * w1[(k + 3) * D + lane];
      }
      float tr = fmaxf(b0_ + (h0 + h1) + (h2 + h3), 0.f);
      float g0 = 0.f, g1 = 0.f, g2 = 0.f, g3 = 0.f;
#pragma unroll 4
      for (int k = 0; k < D; k += 4) {
        g0 += __shfl(tr, k, 64) * w2[k * D + lane];
        g1 += __shfl(tr, k + 1, 64) * w2[(k + 1) * D + lane];
        g2 += __shfl(tr, k + 2, 64) * w2[(k + 2) * D + lane];
        g3 += __shfl(tr, k + 3, 64) * w2[(k + 3) * D + lane];
      }
      a2 = ((const float*)rb2)[lane] + (g0 + g1) + (g2 + g3);
    } else {
      const __hip_bfloat16* w1 = (const __hip_bfloat16*)rW1;
      const __hip_bfloat16* w2 = (const __hip_bfloat16*)rW2;
#pragma unroll 4
      for (int k = 0; k < D; k += 4) {
        h0 += __shfl(xv, k, 64) * __bfloat162float(w1[k * D + lane]);
        h1 += __shfl(xv, k + 1, 64) * __bfloat162float(w1[(k + 1) * D + lane]);
        h2 += __shfl(xv, k + 2, 64) * __bfloat162float(w1[(k + 2) * D + lane]);
        h3 += __shfl(xv, k + 3, 64) * __bfloat162float(w1[(k + 3) * D + lane]);
      }
      float tr = fmaxf(b0_ + (h0 + h1) + (h2 + h3), 0.f);
      float g0 = 0.f, g1 = 0.f, g2 = 0.f, g3 = 0.f;
#pragma unroll 4
      for (int k = 0; k < D; k += 4) {
        g0 += __shfl(tr, k, 64) * __bfloat162float(w2[k * D + lane]);
        g1 += __shfl(tr, k + 1, 64) * __bfloat162float(w2[(k + 1) * D + lane]);
        g2 += __shfl(tr, k + 2, 64) * __bfloat162float(w2[(k + 2) * D + lane]);
        g3 += __shfl(tr, k + 3, 64) * __bfloat162float(w2[(k + 3) * D + lane]);
      }
      a2 = __bfloat162float(((const __hip_bfloat16*)rb2)[lane]) + (g0 + g1) + (g2 + g3);
    }
    stv(out, (size_t)wid * D + lane, f32, sane(v + a2));
  } else {
    v = elu1(v);  // inter-layer elu
    if (mode == 0) {
      prep_node(sane(v), f32, wid, lane, Wn, attn, fh2, Hm2, al2, ar2);
    } else {
      stv(out, (size_t)wid * D + lane, f32, sane(v));
    }
  }
}

extern "C" void kernel_launch(void* const* d_in, const int* in_sizes, int n_in,
                              void* d_out, int out_size, void* d_ws, size_t ws_size,
                              hipStream_t stream) {
  const void* x = d_in[0];
  const int* ei = (const int*)d_in[1];
  const void* w = d_in[2];
  const void* W0 = d_in[3];
  const void* att0 = d_in[4];
  const void* beta0 = d_in[5];
  const void* b0 = d_in[6];
  const void* W1 = d_in[7];
  const void* att1 = d_in[8];
  const void* beta1 = d_in[9];
  const void* b1 = d_in[10];
  const void* rW1 = d_in[11];
  const void* rb1 = d_in[12];
  const void* rW2 = d_in[13];
  const void* rb2 = d_in[14];

  const int N = in_sizes[0] / D;
  const int E = in_sizes[2];

  char* base = (char*)d_ws;
  size_t off = 0;
  auto alloc = [&](size_t bytes) -> void* {
    void* p = base + off;
    off += (bytes + 255) & ~(size_t)255;
    return p;
  };
  // always-needed tier
  int* flags = (int*)alloc(256);
  int* cnt = (int*)alloc((size_t)N * 4);
  unsigned int* csr2 = (unsigned int*)alloc((size_t)N * CAP * 4);
  unsigned char* fhat = (unsigned char*)alloc((size_t)N * D);
  __hip_bfloat16* Hmat = (__hip_bfloat16*)alloc((size_t)N * D * 2);
  float* a_l = (float*)alloc((size_t)N * 4);
  float* a_r = (float*)alloc((size_t)N * 4);
  // fused tier (second-layer prep buffers)
  unsigned char* fhat2 = (unsigned char*)alloc((size_t)N * D);
  __hip_bfloat16* Hmat2 = (__hip_bfloat16*)alloc((size_t)N * D * 2);
  float* a_l2 = (float*)alloc((size_t)N * 4);
  float* a_r2 = (float*)alloc((size_t)N * 4);
  const bool fused = (off <= ws_size);

  const int nb = (N + 3) / 4;

  hipMemsetAsync(cnt, 0, (size_t)N * 4, stream);
  k_all<<<nb, 256, 0, stream>>>((const unsigned short*)x, ei, w, flags, cnt,
                                x, W0, att0, fhat, Hmat, a_l, a_r, csr2, N, E);

  if (fused) {
    k_edge<<<N, 64, 0, stream>>>(cnt, csr2, ei, w, fhat, Hmat, a_l, a_r,
                                 beta0, b0, x, rW1, rb1, rW2, rb2,
                                 W1, att1, fhat2, Hmat2, a_l2, a_r2,
                                 flags, d_out, N, E, 0);
    k_edge<<<N, 64, 0, stream>>>(cnt, csr2, ei, w, fhat2, Hmat2, a_l2, a_r2,
                                 beta1, b1, x, rW1, rb1, rW2, rb2,
                                 nullptr, nullptr, nullptr, nullptr, nullptr, nullptr,
                                 flags, d_out, N, E, 1);
  } else {
    k_edge<<<N, 64, 0, stream>>>(cnt, csr2, ei, w, fhat, Hmat, a_l, a_r,
                                 beta0, b0, x, rW1, rb1, rW2, rb2,
                                 nullptr, nullptr, nullptr, nullptr, nullptr, nullptr,
                                 flags, d_out, N, E, 2);
    k_prep<<<nb, 256, 0, stream>>>(d_out, W1, att1, flags, fhat, Hmat, a_l, a_r, N);
    k_edge<<<N, 64, 0, stream>>>(cnt, csr2, ei, w, fhat, Hmat, a_l, a_r,
                                 beta1, b1, x, rW1, rb1, rW2, rb2,
                                 nullptr, nullptr, nullptr, nullptr, nullptr, nullptr,
                                 flags, d_out, N, E, 1);
  }
}

// Round 5
// 368.004 us; speedup vs baseline: 1.4115x; 1.1110x over previous
//
#include <hip/hip_runtime.h>
#include <hip/hip_bf16.h>
#include <math.h>

// COSGATEncoder: N=50000, E=1280000, D=64, HEADS=1. f32 in/out (runtime-detected,
// bf16 fallback), edge_index int64 (runtime-detected, int32 fallback).
// R17: (1) k_all goes 64-thread wave-synchronous (grid=N, ballot-based dtype
// detect, no syncthreads/LDS) — same occupancy lever that took k_edge 141->129
// in R16. (2) k_edge issue-count cuts: 32-bit byte offsets for gathers, phase-2
// reads csr2 directly (phase-1 sg writes dropped), Hmat rows register-prefetched
// in phase-1 iters 0-3 (hm[4], 16 VGPR, static idx; phase 3 load-free for
// deg<=32 ~ 91% of nodes; VGPR ~52 under the (64,8) cap of 64 — unlike R13's
// 256-thread spill). Rest = R16: slot-CSR (memset, k_all, k_edge x2), exact
// slow path deg>CAP, 4-chain ILP prep/MLP, fp8 fhat rows, packed 4B csr.

constexpr int D = 64;
constexpr int CAP = 64;
constexpr float NEG_SLOPE = 0.2f;
constexpr float EPS_COS = 1e-8f;
constexpr float EPS_SM = 1e-16f;

#if defined(__has_builtin)
#if __has_builtin(__builtin_amdgcn_cvt_pk_f32_fp8) && __has_builtin(__builtin_amdgcn_cvt_pk_fp8_f32)
#define HW_FP8 1
#endif
#endif

typedef float floatx2 __attribute__((ext_vector_type(2)));

__device__ __forceinline__ float wred_sum(float v) {
#pragma unroll
  for (int off = 32; off > 0; off >>= 1) v += __shfl_xor(v, off, 64);
  return v;
}
__device__ __forceinline__ float wred_max(float v) {
#pragma unroll
  for (int off = 32; off > 0; off >>= 1) v = fmaxf(v, __shfl_xor(v, off, 64));
  return v;
}
__device__ __forceinline__ float elu1(float x) { return x > 0.f ? x : __expf(x) - 1.f; }
__device__ __forceinline__ float sane(float v) {
  return (v == v && fabsf(v) < 1e30f) ? v : 0.f;
}
__device__ __forceinline__ float ldv(const void* p, size_t i, int f32) {
  return f32 ? ((const float*)p)[i]
             : __bfloat162float(((const __hip_bfloat16*)p)[i]);
}
__device__ __forceinline__ void stv(void* p, size_t i, int f32, float v) {
  if (f32) ((float*)p)[i] = v;
  else ((__hip_bfloat16*)p)[i] = __float2bfloat16(v);
}
__device__ __forceinline__ float b2f(unsigned short u) {
  return __uint_as_float(((unsigned int)u) << 16);
}
__device__ __forceinline__ void unp8(uint4 u, float* f) {
  f[0] = __uint_as_float(u.x << 16);
  f[1] = __uint_as_float(u.x & 0xffff0000u);
  f[2] = __uint_as_float(u.y << 16);
  f[3] = __uint_as_float(u.y & 0xffff0000u);
  f[4] = __uint_as_float(u.z << 16);
  f[5] = __uint_as_float(u.z & 0xffff0000u);
  f[6] = __uint_as_float(u.w << 16);
  f[7] = __uint_as_float(u.w & 0xffff0000u);
}

// ---- fp8 helpers: HW e4m3 when available, f16-msb (e5m2-like) fallback ----
__device__ __forceinline__ unsigned char enc_fp8(float v) {
#ifdef HW_FP8
  int pk = __builtin_amdgcn_cvt_pk_fp8_f32(v, v, 0, false);
  return (unsigned char)(pk & 0xFF);
#else
  _Float16 h = (_Float16)v;
  unsigned short ub;
  __builtin_memcpy(&ub, &h, 2);
  return (unsigned char)((ub + 0x80) >> 8);  // RNE-ish truncate to top byte
#endif
}
__device__ __forceinline__ void dec_fp8x8(uint2 u, float* f) {
#ifdef HW_FP8
  floatx2 a = __builtin_amdgcn_cvt_pk_f32_fp8(u.x, false);
  floatx2 b = __builtin_amdgcn_cvt_pk_f32_fp8(u.x, true);
  floatx2 c = __builtin_amdgcn_cvt_pk_f32_fp8(u.y, false);
  floatx2 d = __builtin_amdgcn_cvt_pk_f32_fp8(u.y, true);
  f[0] = a[0]; f[1] = a[1]; f[2] = b[0]; f[3] = b[1];
  f[4] = c[0]; f[5] = c[1]; f[6] = d[0]; f[7] = d[1];
#else
#pragma unroll
  for (int i = 0; i < 8; ++i) {
    unsigned int byte = (i < 4 ? (u.x >> (8 * i)) : (u.y >> (8 * (i - 4)))) & 0xFF;
    unsigned short hb = (unsigned short)(byte << 8);
    _Float16 h;
    __builtin_memcpy(&h, &hb, 2);
    f[i] = (float)h;
  }
#endif
}

// packed csr entry: bits 0..17 = src, bits 18..31 = gate quantized to 14 bits
__device__ __forceinline__ unsigned int pack_sg(int src, float g) {
  int gq = (int)(g * 16383.f + 0.5f);
  return ((unsigned int)src & 0x3FFFFu) | ((unsigned int)gq << 18);
}
__device__ __forceinline__ int upk_src(unsigned int e, int N) {
  return min((int)(e & 0x3FFFFu), N - 1);
}
__device__ __forceinline__ float upk_gate(unsigned int e) {
  return (float)(e >> 18) * (1.f / 16383.f);
}
__device__ __forceinline__ float gate_of(float w) {
  return fminf(fmaxf(1.f - 0.25f * fminf(w, 4.f), 0.f), 1.f);
}

// full fp8-row cosine dot (slow path only)
__device__ float slow_cos(const unsigned char* __restrict__ fhat, int a, int b) {
  const uint2* fa = (const uint2*)(fhat + (size_t)a * D);
  const uint2* fb = (const uint2*)(fhat + (size_t)b * D);
  float dsum = 0.f;
  for (int q = 0; q < 8; ++q) {
    float va[8], vb[8];
    dec_fp8x8(fa[q], va);
    dec_fp8x8(fb[q], vb);
#pragma unroll
    for (int i = 0; i < 8; ++i) dsum += va[i] * vb[i];
  }
  return dsum;
}

// shared prep body: node features (lane=feature) -> fhat(fp8), Hmat(bf16), a_l, a_r
__device__ __forceinline__ void prep_node(float f, int f32, int wid, int lane,
                                          const void* __restrict__ W,
                                          const void* __restrict__ att,
                                          unsigned char* __restrict__ fhat,
                                          __hip_bfloat16* __restrict__ Hmat,
                                          float* __restrict__ a_l,
                                          float* __restrict__ a_r) {
  float n2 = wred_sum(f * f);
  float nrm = fmaxf(sqrtf(n2), EPS_COS);
  fhat[(size_t)wid * D + lane] = enc_fp8(f / nrm);
  // 4 independent accumulator chains (dependent-FMA latency / 4)
  float h0 = 0.f, h1 = 0.f, h2 = 0.f, h3 = 0.f;
  if (f32) {
    const float* Wf = (const float*)W;
#pragma unroll 4
    for (int k = 0; k < D; k += 4) {
      h0 += __shfl(f, k, 64) * Wf[k * D + lane];
      h1 += __shfl(f, k + 1, 64) * Wf[(k + 1) * D + lane];
      h2 += __shfl(f, k + 2, 64) * Wf[(k + 2) * D + lane];
      h3 += __shfl(f, k + 3, 64) * Wf[(k + 3) * D + lane];
    }
  } else {
    const __hip_bfloat16* Wb = (const __hip_bfloat16*)W;
#pragma unroll 4
    for (int k = 0; k < D; k += 4) {
      h0 += __shfl(f, k, 64) * __bfloat162float(Wb[k * D + lane]);
      h1 += __shfl(f, k + 1, 64) * __bfloat162float(Wb[(k + 1) * D + lane]);
      h2 += __shfl(f, k + 2, 64) * __bfloat162float(Wb[(k + 2) * D + lane]);
      h3 += __shfl(f, k + 3, 64) * __bfloat162float(Wb[(k + 3) * D + lane]);
    }
  }
  float Hc = (h0 + h1) + (h2 + h3);
  Hmat[(size_t)wid * D + lane] = __float2bfloat16(Hc);
  float al = wred_sum(Hc * ldv(att, lane, f32));
  float ar = wred_sum(Hc * ldv(att, D + lane, f32));
  if (lane == 0) {
    a_l[wid] = al;
    a_r[wid] = ar;
  }
}

// fused, wave-synchronous: dtype detect + edge binning + layer-0 prep.
// 64-thread blocks, grid=N; block b bins edges [b*E/N,(b+1)*E/N) and preps node b.
__global__ void __launch_bounds__(64) k_all(const unsigned short* __restrict__ xu,
                                            const int* __restrict__ ei,
                                            const void* __restrict__ w,
                                            int* __restrict__ flags,
                                            int* __restrict__ cnt,
                                            const void* __restrict__ x,
                                            const void* __restrict__ W,
                                            const void* __restrict__ att,
                                            unsigned char* __restrict__ fhat,
                                            __hip_bfloat16* __restrict__ Hmat,
                                            float* __restrict__ a_l,
                                            float* __restrict__ a_r,
                                            unsigned int* __restrict__ csr2,
                                            int N, int E) {
  const int lane = threadIdx.x;
  const int b = blockIdx.x;
  // dtype detect: per-wave, register-only (x[0..63] / ei[0..127] are L2-hot)
  float dv = b2f(xu[lane]);
  float da = fabsf(dv);
  unsigned long long m = __ballot(da > 1e-4f && da < 100.f);
  unsigned long long m2 = __ballot(ei[2 * lane + 1] != 0);
  const int f32 = (__popcll(m) >= 60) ? 0 : 1;
  const int wide = (m2 == 0ull) ? 1 : 0;
  if (b == 0 && lane == 0) {
    flags[0] = f32;
    flags[1] = wide;
  }
  // ---- edge binning: slot via atomicAdd on cnt[dst] ----
  const long long e0 = ((long long)b * E) / N;
  const long long e1 = ((long long)(b + 1) * E) / N;
  for (long long e = e0 + lane; e < e1; e += 64) {
    int ss, dd;
    if (wide) {
      ss = ei[2 * e];
      dd = ei[2 * (size_t)E + 2 * e];
    } else {
      ss = ei[e];
      dd = ei[(size_t)E + e];
    }
    float we = ldv(w, (size_t)e, f32);
    const int dc = min(max(dd, 0), N - 1);
    const int slot = atomicAdd(&cnt[dc], 1);
    if (slot < CAP)
      csr2[(size_t)dc * CAP + slot] = pack_sg(min(max(ss, 0), N - 1), gate_of(we));
  }
  // ---- node prep: this block's node ----
  if (b < N) {
    float f = ldv(x, (size_t)b * D + lane, f32);
    prep_node(f, f32, b, lane, W, att, fhat, Hmat, a_l, a_r);
  }
}

// standalone prep (non-fused workspace tier)
__global__ void __launch_bounds__(256) k_prep(const void* __restrict__ xin,
                                              const void* __restrict__ W,
                                              const void* __restrict__ att,
                                              const int* __restrict__ flags,
                                              unsigned char* __restrict__ fhat,
                                              __hip_bfloat16* __restrict__ Hmat,
                                              float* __restrict__ a_l,
                                              float* __restrict__ a_r, int N) {
  const int lane = threadIdx.x & 63;
  const int wid = (blockIdx.x * 256 + threadIdx.x) >> 6;
  if (wid >= N) return;
  const int f32 = flags[0];
  float f = ldv(xin, (size_t)wid * D + lane, f32);
  prep_node(f, f32, wid, lane, W, att, fhat, Hmat, a_l, a_r);
}

// ---------------- edge kernel: ONE wave per dst node (64-thread blocks) ----------------
// R17: 32-bit gather offsets; Hmat register-prefetch hm[4] (iters 0-3) so phase 3
// is load-free for deg<=32; phase 2 reads csr2 directly (no phase-1 sg writes).
__global__ void __launch_bounds__(64, 8) k_edge(const int* __restrict__ cnt,
                                                const unsigned int* __restrict__ csr2,
                                                const int* __restrict__ ei,
                                                const void* __restrict__ w,
                                                const unsigned char* __restrict__ fhat,
                                                const __hip_bfloat16* __restrict__ Hmat,
                                                const float* __restrict__ a_l,
                                                const float* __restrict__ a_r,
                                                const void* __restrict__ beta,
                                                const void* __restrict__ bias,
                                                const void* __restrict__ x,
                                                const void* __restrict__ rW1,
                                                const void* __restrict__ rb1,
                                                const void* __restrict__ rW2,
                                                const void* __restrict__ rb2,
                                                const void* __restrict__ Wn,
                                                const void* __restrict__ attn,
                                                unsigned char* __restrict__ fh2,
                                                __hip_bfloat16* __restrict__ Hm2,
                                                float* __restrict__ al2,
                                                float* __restrict__ ar2,
                                                const int* __restrict__ flags,
                                                void* __restrict__ out,
                                                int N, int E, int mode) {
  const int lane = threadIdx.x;
  const int wid = blockIdx.x;
  __shared__ float2 lc[CAP];  // (l, c) per edge
  __shared__ float2 sg[CAP];  // (src bits, p) — written in phase 2
  __shared__ float lds_t[D];
  if (wid >= N) return;
  const int f32 = flags[0];
  const int g = lane >> 3;   // edge slot in 8-edge group
  const int sub = lane & 7;  // feature block: [8*sub, 8*sub+8)
  const int degRaw = cnt[wid];
  const float aln = a_l[wid];
  const float bb = 1.f / (1.f + __expf(-ldv(beta, 0, f32)));
  const float ob = 1.f - bb;
  const char* HmatB = (const char*)Hmat;

  float v;  // pre-elu output feature for this lane
  if (degRaw <= CAP) {
    // ================= fast path (always taken on bench data) =================
    const int deg = degRaw;
    const int s = wid * CAP;
    float fn[8];
    dec_fp8x8(*(const uint2*)(fhat + (((unsigned)wid << 6) | ((unsigned)sub << 3))), fn);

    // ---- phase 1 (iters 0-3, static): fp8 gathers + Hmat prefetch to regs ----
    float m1 = -1e30f, m2 = -1e30f;
    uint4 hm[4];
#pragma unroll
    for (int kk = 0; kk < 4; ++kk) {
      const int base = kk * 8;
      if (base < deg) {
        const int j = base + g;
        const bool val = j < deg;
        const unsigned int en = val ? csr2[s + j] : (unsigned int)wid;
        const unsigned src = (unsigned)upk_src(en, N);
        float hv[8];
        dec_fp8x8(*(const uint2*)(fhat + ((src << 6) | ((unsigned)sub << 3))), hv);
        hm[kk] = *(const uint4*)(HmatB + ((src << 7) | ((unsigned)sub << 4)));
        float d = 0.f;
#pragma unroll
        for (int i = 0; i < 8; ++i) d += fn[i] * hv[i];
        d += __shfl_xor(d, 1, 64);
        d += __shfl_xor(d, 2, 64);
        d += __shfl_xor(d, 4, 64);
        float l = aln + a_r[src];
        l = (l >= 0.f) ? l : NEG_SLOPE * l;
        if (val) {
          m1 = fmaxf(m1, l);
          m2 = fmaxf(m2, d);
          if (sub == 0) lc[j] = make_float2(l, d);
        }
      }
    }
    // tail iterations (deg > 32): no prefetch
    for (int base = 32; base < deg; base += 8) {
      const int j = base + g;
      const bool val = j < deg;
      const unsigned int en = val ? csr2[s + j] : (unsigned int)wid;
      const unsigned src = (unsigned)upk_src(en, N);
      float hv[8];
      dec_fp8x8(*(const uint2*)(fhat + ((src << 6) | ((unsigned)sub << 3))), hv);
      float d = 0.f;
#pragma unroll
      for (int i = 0; i < 8; ++i) d += fn[i] * hv[i];
      d += __shfl_xor(d, 1, 64);
      d += __shfl_xor(d, 2, 64);
      d += __shfl_xor(d, 4, 64);
      float l = aln + a_r[src];
      l = (l >= 0.f) ? l : NEG_SLOPE * l;
      if (val) {
        m1 = fmaxf(m1, l);
        m2 = fmaxf(m2, d);
        if (sub == 0) lc[j] = make_float2(l, d);
      }
    }
    m1 = fmaxf(m1, __shfl_xor(m1, 8, 64));
    m1 = fmaxf(m1, __shfl_xor(m1, 16, 64));
    m1 = fmaxf(m1, __shfl_xor(m1, 32, 64));
    m2 = fmaxf(m2, __shfl_xor(m2, 8, 64));
    m2 = fmaxf(m2, __shfl_xor(m2, 16, 64));
    m2 = fmaxf(m2, __shfl_xor(m2, 32, 64));

    // ---- phase 2: dual softmax sums + fused p (deg <= 64 always) ----
    float el0 = 0.f, ec0 = 0.f, gg0 = 0.f;
    int q0 = 0;
    float ps1 = 0.f, ps2 = 0.f;
    if (lane < deg) {
      const unsigned int en = csr2[s + lane];  // coalesced, L2-hot
      q0 = upk_src(en, N);
      gg0 = upk_gate(en);
      float2 t = lc[lane];
      el0 = __expf(t.x - m1);
      ec0 = __expf(t.y - m2);
      ps1 = el0;
      ps2 = ec0;
    }
    const float rs1 = 1.f / (wred_sum(ps1) + EPS_SM);
    const float rs2 = 1.f / (wred_sum(ps2) + EPS_SM);

    float sp = 0.f;
    if (lane < deg) {
      float tt = (ob * el0 * rs1 + bb * ec0 * rs2) * gg0;
      float p0 = __expf(tt - 1.f);
      sp = p0;
      sg[lane] = make_float2(__int_as_float(q0), p0);  // (src, p)
    }
    const float rinv = 1.f / (wred_sum(sp) + EPS_SM);

    // ---- phase 3: register-resident Hmat for iters 0-3; gathers for tail ----
    float acc[8] = {0.f, 0.f, 0.f, 0.f, 0.f, 0.f, 0.f, 0.f};
#pragma unroll
    for (int kk = 0; kk < 4; ++kk) {
      const int base = kk * 8;
      if (base < deg) {
        const int j = base + g;
        const float pv = (j < deg) ? sg[j].y : 0.f;
        float hv[8];
        unp8(hm[kk], hv);
#pragma unroll
        for (int i = 0; i < 8; ++i) acc[i] += pv * hv[i];
      }
    }
    for (int base = 32; base < deg; base += 8) {
      const int j = base + g;
      float2 en = (j < deg) ? sg[j] : make_float2(__int_as_float(wid), 0.f);
      const float pv = en.y;
      const unsigned srcv = (unsigned)__float_as_int(en.x);
      float hv[8];
      unp8(*(const uint4*)(HmatB + ((srcv << 7) | ((unsigned)sub << 4))), hv);
#pragma unroll
      for (int i = 0; i < 8; ++i) acc[i] += pv * hv[i];
    }
#pragma unroll
    for (int i = 0; i < 8; ++i) {
      acc[i] += __shfl_xor(acc[i], 8, 64);
      acc[i] += __shfl_xor(acc[i], 16, 64);
      acc[i] += __shfl_xor(acc[i], 32, 64);
    }
    if (g == 0) {
#pragma unroll
      for (int i = 0; i < 8; ++i) lds_t[8 * sub + i] = acc[i];
    }
    v = lds_t[lane] * rinv + ldv(bias, lane, f32);
  } else {
    // ============ slow path: exact 3-pass over raw edge list ============
    // (deg > CAP; probability ~1e-10 on Poisson(25.6) data — correctness only)
    const int wide = flags[1];
    lds_t[lane] = 0.f;
    float m1 = -1e30f, m2 = -1e30f;
    for (int e64 = lane; e64 < E; e64 += 64) {
      int dd = wide ? ei[2 * (size_t)E + 2 * (size_t)e64] : ei[(size_t)E + e64];
      if (dd != wid) continue;
      int ss = wide ? ei[2 * (size_t)e64] : ei[e64];
      ss = min(max(ss, 0), N - 1);
      float l = aln + a_r[ss];
      l = (l >= 0.f) ? l : NEG_SLOPE * l;
      float c = slow_cos(fhat, wid, ss);
      m1 = fmaxf(m1, l);
      m2 = fmaxf(m2, c);
    }
    m1 = wred_max(m1);
    m2 = wred_max(m2);
    float ps1 = 0.f, ps2 = 0.f;
    for (int e64 = lane; e64 < E; e64 += 64) {
      int dd = wide ? ei[2 * (size_t)E + 2 * (size_t)e64] : ei[(size_t)E + e64];
      if (dd != wid) continue;
      int ss = wide ? ei[2 * (size_t)e64] : ei[e64];
      ss = min(max(ss, 0), N - 1);
      float l = aln + a_r[ss];
      l = (l >= 0.f) ? l : NEG_SLOPE * l;
      float c = slow_cos(fhat, wid, ss);
      ps1 += __expf(l - m1);
      ps2 += __expf(c - m2);
    }
    const float rs1 = 1.f / (wred_sum(ps1) + EPS_SM);
    const float rs2 = 1.f / (wred_sum(ps2) + EPS_SM);
    float sp = 0.f;
    for (int e64 = lane; e64 < E; e64 += 64) {
      int dd = wide ? ei[2 * (size_t)E + 2 * (size_t)e64] : ei[(size_t)E + e64];
      if (dd != wid) continue;
      int ss = wide ? ei[2 * (size_t)e64] : ei[e64];
      ss = min(max(ss, 0), N - 1);
      float l = aln + a_r[ss];
      l = (l >= 0.f) ? l : NEG_SLOPE * l;
      float c = slow_cos(fhat, wid, ss);
      float gx = gate_of(ldv(w, e64, f32));
      float px = __expf((ob * __expf(l - m1) * rs1 + bb * __expf(c - m2) * rs2) * gx - 1.f);
      sp += px;
      for (int q = 0; q < D; ++q)
        atomicAdd(&lds_t[q], px * __bfloat162float(Hmat[(size_t)ss * D + q]));
    }
    const float rinv = 1.f / (wred_sum(sp) + EPS_SM);
    v = lds_t[lane] * rinv + ldv(bias, lane, f32);
  }

  v = elu1(v);  // elu inside _cosgat
  if (mode == 1) {
    // fused residual MLP: relu(x@rW1+rb1)@rW2+rb2 (4-chain ILP)
    float xv = ldv(x, (size_t)wid * D + lane, f32);
    float a2;
    float b0_ = ldv(rb1, lane, f32);
    float h0 = 0.f, h1 = 0.f, h2 = 0.f, h3 = 0.f;
    if (f32) {
      const float* w1 = (const float*)rW1;
      const float* w2 = (const float*)rW2;
#pragma unroll 4
      for (int k = 0; k < D; k += 4) {
        h0 += __shfl(xv, k, 64) * w1[k * D + lane];
        h1 += __shfl(xv, k + 1, 64) * w1[(k + 1) * D + lane];
        h2 += __shfl(xv, k + 2, 64) * w1[(k + 2) * D + lane];
        h3 += __shfl(xv, k + 3, 64) * w1[(k + 3) * D + lane];
      }
      float tr = fmaxf(b0_ + (h0 + h1) + (h2 + h3), 0.f);
      float g0 = 0.f, g1 = 0.f, g2 = 0.f, g3 = 0.f;
#pragma unroll 4
      for (int k = 0; k < D; k += 4) {
        g0 += __shfl(tr, k, 64) * w2[k * D + lane];
        g1 += __shfl(tr, k + 1, 64) * w2[(k + 1) * D + lane];
        g2 += __shfl(tr, k + 2, 64) * w2[(k + 2) * D + lane];
        g3 += __shfl(tr, k + 3, 64) * w2[(k + 3) * D + lane];
      }
      a2 = ((const float*)rb2)[lane] + (g0 + g1) + (g2 + g3);
    } else {
      const __hip_bfloat16* w1 = (const __hip_bfloat16*)rW1;
      const __hip_bfloat16* w2 = (const __hip_bfloat16*)rW2;
#pragma unroll 4
      for (int k = 0; k < D; k += 4) {
        h0 += __shfl(xv, k, 64) * __bfloat162float(w1[k * D + lane]);
        h1 += __shfl(xv, k + 1, 64) * __bfloat162float(w1[(k + 1) * D + lane]);
        h2 += __shfl(xv, k + 2, 64) * __bfloat162float(w1[(k + 2) * D + lane]);
        h3 += __shfl(xv, k + 3, 64) * __bfloat162float(w1[(k + 3) * D + lane]);
      }
      float tr = fmaxf(b0_ + (h0 + h1) + (h2 + h3), 0.f);
      float g0 = 0.f, g1 = 0.f, g2 = 0.f, g3 = 0.f;
#pragma unroll 4
      for (int k = 0; k < D; k += 4) {
        g0 += __shfl(tr, k, 64) * __bfloat162float(w2[k * D + lane]);
        g1 += __shfl(tr, k + 1, 64) * __bfloat162float(w2[(k + 1) * D + lane]);
        g2 += __shfl(tr, k + 2, 64) * __bfloat162float(w2[(k + 2) * D + lane]);
        g3 += __shfl(tr, k + 3, 64) * __bfloat162float(w2[(k + 3) * D + lane]);
      }
      a2 = __bfloat162float(((const __hip_bfloat16*)rb2)[lane]) + (g0 + g1) + (g2 + g3);
    }
    stv(out, (size_t)wid * D + lane, f32, sane(v + a2));
  } else {
    v = elu1(v);  // inter-layer elu
    if (mode == 0) {
      prep_node(sane(v), f32, wid, lane, Wn, attn, fh2, Hm2, al2, ar2);
    } else {
      stv(out, (size_t)wid * D + lane, f32, sane(v));
    }
  }
}

extern "C" void kernel_launch(void* const* d_in, const int* in_sizes, int n_in,
                              void* d_out, int out_size, void* d_ws, size_t ws_size,
                              hipStream_t stream) {
  const void* x = d_in[0];
  const int* ei = (const int*)d_in[1];
  const void* w = d_in[2];
  const void* W0 = d_in[3];
  const void* att0 = d_in[4];
  const void* beta0 = d_in[5];
  const void* b0 = d_in[6];
  const void* W1 = d_in[7];
  const void* att1 = d_in[8];
  const void* beta1 = d_in[9];
  const void* b1 = d_in[10];
  const void* rW1 = d_in[11];
  const void* rb1 = d_in[12];
  const void* rW2 = d_in[13];
  const void* rb2 = d_in[14];

  const int N = in_sizes[0] / D;
  const int E = in_sizes[2];

  char* base = (char*)d_ws;
  size_t off = 0;
  auto alloc = [&](size_t bytes) -> void* {
    void* p = base + off;
    off += (bytes + 255) & ~(size_t)255;
    return p;
  };
  // always-needed tier
  int* flags = (int*)alloc(256);
  int* cnt = (int*)alloc((size_t)N * 4);
  unsigned int* csr2 = (unsigned int*)alloc((size_t)N * CAP * 4);
  unsigned char* fhat = (unsigned char*)alloc((size_t)N * D);
  __hip_bfloat16* Hmat = (__hip_bfloat16*)alloc((size_t)N * D * 2);
  float* a_l = (float*)alloc((size_t)N * 4);
  float* a_r = (float*)alloc((size_t)N * 4);
  // fused tier (second-layer prep buffers)
  unsigned char* fhat2 = (unsigned char*)alloc((size_t)N * D);
  __hip_bfloat16* Hmat2 = (__hip_bfloat16*)alloc((size_t)N * D * 2);
  float* a_l2 = (float*)alloc((size_t)N * 4);
  float* a_r2 = (float*)alloc((size_t)N * 4);
  const bool fused = (off <= ws_size);

  hipMemsetAsync(cnt, 0, (size_t)N * 4, stream);
  k_all<<<N, 64, 0, stream>>>((const unsigned short*)x, ei, w, flags, cnt,
                              x, W0, att0, fhat, Hmat, a_l, a_r, csr2, N, E);

  if (fused) {
    k_edge<<<N, 64, 0, stream>>>(cnt, csr2, ei, w, fhat, Hmat, a_l, a_r,
                                 beta0, b0, x, rW1, rb1, rW2, rb2,
                                 W1, att1, fhat2, Hmat2, a_l2, a_r2,
                                 flags, d_out, N, E, 0);
    k_edge<<<N, 64, 0, stream>>>(cnt, csr2, ei, w, fhat2, Hmat2, a_l2, a_r2,
                                 beta1, b1, x, rW1, rb1, rW2, rb2,
                                 nullptr, nullptr, nullptr, nullptr, nullptr, nullptr,
                                 flags, d_out, N, E, 1);
  } else {
    const int nb = (N + 3) / 4;
    k_edge<<<N, 64, 0, stream>>>(cnt, csr2, ei, w, fhat, Hmat, a_l, a_r,
                                 beta0, b0, x, rW1, rb1, rW2, rb2,
                                 nullptr, nullptr, nullptr, nullptr, nullptr, nullptr,
                                 flags, d_out, N, E, 2);
    k_prep<<<nb, 256, 0, stream>>>(d_out, W1, att1, flags, fhat, Hmat, a_l, a_r, N);
    k_edge<<<N, 64, 0, stream>>>(cnt, csr2, ei, w, fhat, Hmat, a_l, a_r,
                                 beta1, b1, x, rW1, rb1, rW2, rb2,
                                 nullptr, nullptr, nullptr, nullptr, nullptr, nullptr,
                                 flags, d_out, N, E, 1);
  }
}

// Round 6
// 321.092 us; speedup vs baseline: 1.6177x; 1.1461x over previous
//
#include <hip/hip_runtime.h>
#include <hip/hip_bf16.h>
#include <math.h>

// COSGATEncoder: N=50000, E=1280000, D=64, HEADS=1. f32 in/out (runtime-detected,
// bf16 fallback), edge_index int64 (runtime-detected, int32 fallback).
// R18: LDS-broadcast matmuls. Every shuffle-broadcast GEMM (prep_node H=x@W,
// residual MLP) replaced by stage-row-to-LDS + ds_read immediate-offset
// broadcast: ls[lane]=f; h += ls[k]*W[k][lane]. 4 consecutive ls reads fold to
// one ds_read_b128 -> inner loop ~192 ops -> ~80 ops (no v_mov+ds_bpermute per
// k). Rationale: waves are ~90% queue-stalled (R17: occupancy 81%, VALU 44%,
// all phase restructures neutral); epilogue ops share the contended VMEM/DS
// pipes, so cutting them is the remaining per-wave lever. Phases 1-3 = R17.
// Rest = R17/R16/R15: 64-thd wave-sync k_all + k_edge, slot-CSR (4 dispatches),
// exact slow path deg>CAP, fp8 fhat rows, packed 4B csr.

constexpr int D = 64;
constexpr int CAP = 64;
constexpr float NEG_SLOPE = 0.2f;
constexpr float EPS_COS = 1e-8f;
constexpr float EPS_SM = 1e-16f;

#if defined(__has_builtin)
#if __has_builtin(__builtin_amdgcn_cvt_pk_f32_fp8) && __has_builtin(__builtin_amdgcn_cvt_pk_fp8_f32)
#define HW_FP8 1
#endif
#endif

typedef float floatx2 __attribute__((ext_vector_type(2)));

__device__ __forceinline__ float wred_sum(float v) {
#pragma unroll
  for (int off = 32; off > 0; off >>= 1) v += __shfl_xor(v, off, 64);
  return v;
}
__device__ __forceinline__ float wred_max(float v) {
#pragma unroll
  for (int off = 32; off > 0; off >>= 1) v = fmaxf(v, __shfl_xor(v, off, 64));
  return v;
}
__device__ __forceinline__ float elu1(float x) { return x > 0.f ? x : __expf(x) - 1.f; }
__device__ __forceinline__ float sane(float v) {
  return (v == v && fabsf(v) < 1e30f) ? v : 0.f;
}
__device__ __forceinline__ float ldv(const void* p, size_t i, int f32) {
  return f32 ? ((const float*)p)[i]
             : __bfloat162float(((const __hip_bfloat16*)p)[i]);
}
__device__ __forceinline__ void stv(void* p, size_t i, int f32, float v) {
  if (f32) ((float*)p)[i] = v;
  else ((__hip_bfloat16*)p)[i] = __float2bfloat16(v);
}
__device__ __forceinline__ float b2f(unsigned short u) {
  return __uint_as_float(((unsigned int)u) << 16);
}
__device__ __forceinline__ void unp8(uint4 u, float* f) {
  f[0] = __uint_as_float(u.x << 16);
  f[1] = __uint_as_float(u.x & 0xffff0000u);
  f[2] = __uint_as_float(u.y << 16);
  f[3] = __uint_as_float(u.y & 0xffff0000u);
  f[4] = __uint_as_float(u.z << 16);
  f[5] = __uint_as_float(u.z & 0xffff0000u);
  f[6] = __uint_as_float(u.w << 16);
  f[7] = __uint_as_float(u.w & 0xffff0000u);
}

// ---- fp8 helpers: HW e4m3 when available, f16-msb (e5m2-like) fallback ----
__device__ __forceinline__ unsigned char enc_fp8(float v) {
#ifdef HW_FP8
  int pk = __builtin_amdgcn_cvt_pk_fp8_f32(v, v, 0, false);
  return (unsigned char)(pk & 0xFF);
#else
  _Float16 h = (_Float16)v;
  unsigned short ub;
  __builtin_memcpy(&ub, &h, 2);
  return (unsigned char)((ub + 0x80) >> 8);  // RNE-ish truncate to top byte
#endif
}
__device__ __forceinline__ void dec_fp8x8(uint2 u, float* f) {
#ifdef HW_FP8
  floatx2 a = __builtin_amdgcn_cvt_pk_f32_fp8(u.x, false);
  floatx2 b = __builtin_amdgcn_cvt_pk_f32_fp8(u.x, true);
  floatx2 c = __builtin_amdgcn_cvt_pk_f32_fp8(u.y, false);
  floatx2 d = __builtin_amdgcn_cvt_pk_f32_fp8(u.y, true);
  f[0] = a[0]; f[1] = a[1]; f[2] = b[0]; f[3] = b[1];
  f[4] = c[0]; f[5] = c[1]; f[6] = d[0]; f[7] = d[1];
#else
#pragma unroll
  for (int i = 0; i < 8; ++i) {
    unsigned int byte = (i < 4 ? (u.x >> (8 * i)) : (u.y >> (8 * (i - 4)))) & 0xFF;
    unsigned short hb = (unsigned short)(byte << 8);
    _Float16 h;
    __builtin_memcpy(&h, &hb, 2);
    f[i] = (float)h;
  }
#endif
}

// packed csr entry: bits 0..17 = src, bits 18..31 = gate quantized to 14 bits
__device__ __forceinline__ unsigned int pack_sg(int src, float g) {
  int gq = (int)(g * 16383.f + 0.5f);
  return ((unsigned int)src & 0x3FFFFu) | ((unsigned int)gq << 18);
}
__device__ __forceinline__ int upk_src(unsigned int e, int N) {
  return min((int)(e & 0x3FFFFu), N - 1);
}
__device__ __forceinline__ float upk_gate(unsigned int e) {
  return (float)(e >> 18) * (1.f / 16383.f);
}
__device__ __forceinline__ float gate_of(float w) {
  return fminf(fmaxf(1.f - 0.25f * fminf(w, 4.f), 0.f), 1.f);
}

// full fp8-row cosine dot (slow path only)
__device__ float slow_cos(const unsigned char* __restrict__ fhat, int a, int b) {
  const uint2* fa = (const uint2*)(fhat + (size_t)a * D);
  const uint2* fb = (const uint2*)(fhat + (size_t)b * D);
  float dsum = 0.f;
  for (int q = 0; q < 8; ++q) {
    float va[8], vb[8];
    dec_fp8x8(fa[q], va);
    dec_fp8x8(fb[q], vb);
#pragma unroll
    for (int i = 0; i < 8; ++i) dsum += va[i] * vb[i];
  }
  return dsum;
}

// shared prep body: node features (lane=feature) -> fhat(fp8), Hmat(bf16), a_l, a_r
// ls: 64-float LDS scratch (row staged once; ds_read-broadcast in the GEMM loop)
__device__ __forceinline__ void prep_node(float f, int f32, int wid, int lane,
                                          const void* __restrict__ W,
                                          const void* __restrict__ att,
                                          unsigned char* __restrict__ fhat,
                                          __hip_bfloat16* __restrict__ Hmat,
                                          float* __restrict__ a_l,
                                          float* __restrict__ a_r,
                                          float* __restrict__ ls) {
  float n2 = wred_sum(f * f);
  float nrm = fmaxf(sqrtf(n2), EPS_COS);
  fhat[(size_t)wid * D + lane] = enc_fp8(f / nrm);
  ls[lane] = f;
  __syncthreads();  // 1-wave block: waitcnt only
  float h0 = 0.f, h1 = 0.f, h2 = 0.f, h3 = 0.f;
  if (f32) {
    const float* Wf = (const float*)W;
#pragma unroll 4
    for (int k = 0; k < D; k += 4) {
      h0 += ls[k] * Wf[k * D + lane];
      h1 += ls[k + 1] * Wf[(k + 1) * D + lane];
      h2 += ls[k + 2] * Wf[(k + 2) * D + lane];
      h3 += ls[k + 3] * Wf[(k + 3) * D + lane];
    }
  } else {
    const __hip_bfloat16* Wb = (const __hip_bfloat16*)W;
#pragma unroll 4
    for (int k = 0; k < D; k += 4) {
      h0 += ls[k] * __bfloat162float(Wb[k * D + lane]);
      h1 += ls[k + 1] * __bfloat162float(Wb[(k + 1) * D + lane]);
      h2 += ls[k + 2] * __bfloat162float(Wb[(k + 2) * D + lane]);
      h3 += ls[k + 3] * __bfloat162float(Wb[(k + 3) * D + lane]);
    }
  }
  float Hc = (h0 + h1) + (h2 + h3);
  Hmat[(size_t)wid * D + lane] = __float2bfloat16(Hc);
  float al = wred_sum(Hc * ldv(att, lane, f32));
  float ar = wred_sum(Hc * ldv(att, D + lane, f32));
  if (lane == 0) {
    a_l[wid] = al;
    a_r[wid] = ar;
  }
  __syncthreads();  // caller may reuse ls
}

// fused, wave-synchronous: dtype detect + edge binning + layer-0 prep.
// 64-thread blocks, grid=N; block b bins edges [b*E/N,(b+1)*E/N) and preps node b.
__global__ void __launch_bounds__(64) k_all(const unsigned short* __restrict__ xu,
                                            const int* __restrict__ ei,
                                            const void* __restrict__ w,
                                            int* __restrict__ flags,
                                            int* __restrict__ cnt,
                                            const void* __restrict__ x,
                                            const void* __restrict__ W,
                                            const void* __restrict__ att,
                                            unsigned char* __restrict__ fhat,
                                            __hip_bfloat16* __restrict__ Hmat,
                                            float* __restrict__ a_l,
                                            float* __restrict__ a_r,
                                            unsigned int* __restrict__ csr2,
                                            int N, int E) {
  __shared__ float ls[D];
  const int lane = threadIdx.x;
  const int b = blockIdx.x;
  // dtype detect: per-wave, register-only (x[0..63] / ei[0..127] are L2-hot)
  float dv = b2f(xu[lane]);
  float da = fabsf(dv);
  unsigned long long m = __ballot(da > 1e-4f && da < 100.f);
  unsigned long long m2 = __ballot(ei[2 * lane + 1] != 0);
  const int f32 = (__popcll(m) >= 60) ? 0 : 1;
  const int wide = (m2 == 0ull) ? 1 : 0;
  if (b == 0 && lane == 0) {
    flags[0] = f32;
    flags[1] = wide;
  }
  // ---- edge binning: slot via atomicAdd on cnt[dst] ----
  const long long e0 = ((long long)b * E) / N;
  const long long e1 = ((long long)(b + 1) * E) / N;
  for (long long e = e0 + lane; e < e1; e += 64) {
    int ss, dd;
    if (wide) {
      ss = ei[2 * e];
      dd = ei[2 * (size_t)E + 2 * e];
    } else {
      ss = ei[e];
      dd = ei[(size_t)E + e];
    }
    float we = ldv(w, (size_t)e, f32);
    const int dc = min(max(dd, 0), N - 1);
    const int slot = atomicAdd(&cnt[dc], 1);
    if (slot < CAP)
      csr2[(size_t)dc * CAP + slot] = pack_sg(min(max(ss, 0), N - 1), gate_of(we));
  }
  // ---- node prep: this block's node ----
  if (b < N) {
    float f = ldv(x, (size_t)b * D + lane, f32);
    prep_node(f, f32, b, lane, W, att, fhat, Hmat, a_l, a_r, ls);
  }
}

// standalone prep (non-fused workspace tier) — 64-thread, grid=N
__global__ void __launch_bounds__(64) k_prep(const void* __restrict__ xin,
                                             const void* __restrict__ W,
                                             const void* __restrict__ att,
                                             const int* __restrict__ flags,
                                             unsigned char* __restrict__ fhat,
                                             __hip_bfloat16* __restrict__ Hmat,
                                             float* __restrict__ a_l,
                                             float* __restrict__ a_r, int N) {
  __shared__ float ls[D];
  const int lane = threadIdx.x;
  const int wid = blockIdx.x;
  if (wid >= N) return;
  const int f32 = flags[0];
  float f = ldv(xin, (size_t)wid * D + lane, f32);
  prep_node(f, f32, wid, lane, W, att, fhat, Hmat, a_l, a_r, ls);
}

// ---------------- edge kernel: ONE wave per dst node (64-thread blocks) ----------------
__global__ void __launch_bounds__(64, 8) k_edge(const int* __restrict__ cnt,
                                                const unsigned int* __restrict__ csr2,
                                                const int* __restrict__ ei,
                                                const void* __restrict__ w,
                                                const unsigned char* __restrict__ fhat,
                                                const __hip_bfloat16* __restrict__ Hmat,
                                                const float* __restrict__ a_l,
                                                const float* __restrict__ a_r,
                                                const void* __restrict__ beta,
                                                const void* __restrict__ bias,
                                                const void* __restrict__ x,
                                                const void* __restrict__ rW1,
                                                const void* __restrict__ rb1,
                                                const void* __restrict__ rW2,
                                                const void* __restrict__ rb2,
                                                const void* __restrict__ Wn,
                                                const void* __restrict__ attn,
                                                unsigned char* __restrict__ fh2,
                                                __hip_bfloat16* __restrict__ Hm2,
                                                float* __restrict__ al2,
                                                float* __restrict__ ar2,
                                                const int* __restrict__ flags,
                                                void* __restrict__ out,
                                                int N, int E, int mode) {
  const int lane = threadIdx.x;
  const int wid = blockIdx.x;
  __shared__ float2 lc[CAP];  // (l, c) per edge
  __shared__ float2 sg[CAP];  // (src bits, p) — written in phase 2
  __shared__ float lds_t[D];  // acc transpose; reused as GEMM staging in epilogue
  if (wid >= N) return;
  const int f32 = flags[0];
  const int g = lane >> 3;   // edge slot in 8-edge group
  const int sub = lane & 7;  // feature block: [8*sub, 8*sub+8)
  const int degRaw = cnt[wid];
  const float aln = a_l[wid];
  const float bb = 1.f / (1.f + __expf(-ldv(beta, 0, f32)));
  const float ob = 1.f - bb;
  const char* HmatB = (const char*)Hmat;

  float v;  // pre-elu output feature for this lane
  if (degRaw <= CAP) {
    // ================= fast path (always taken on bench data) =================
    const int deg = degRaw;
    const int s = wid * CAP;
    float fn[8];
    dec_fp8x8(*(const uint2*)(fhat + (((unsigned)wid << 6) | ((unsigned)sub << 3))), fn);

    // ---- phase 1 (iters 0-3, static): fp8 gathers + Hmat prefetch to regs ----
    float m1 = -1e30f, m2 = -1e30f;
    uint4 hm[4];
#pragma unroll
    for (int kk = 0; kk < 4; ++kk) {
      const int base = kk * 8;
      if (base < deg) {
        const int j = base + g;
        const bool val = j < deg;
        const unsigned int en = val ? csr2[s + j] : (unsigned int)wid;
        const unsigned src = (unsigned)upk_src(en, N);
        float hv[8];
        dec_fp8x8(*(const uint2*)(fhat + ((src << 6) | ((unsigned)sub << 3))), hv);
        hm[kk] = *(const uint4*)(HmatB + ((src << 7) | ((unsigned)sub << 4)));
        float d = 0.f;
#pragma unroll
        for (int i = 0; i < 8; ++i) d += fn[i] * hv[i];
        d += __shfl_xor(d, 1, 64);
        d += __shfl_xor(d, 2, 64);
        d += __shfl_xor(d, 4, 64);
        float l = aln + a_r[src];
        l = (l >= 0.f) ? l : NEG_SLOPE * l;
        if (val) {
          m1 = fmaxf(m1, l);
          m2 = fmaxf(m2, d);
          if (sub == 0) lc[j] = make_float2(l, d);
        }
      }
    }
    // tail iterations (deg > 32): no prefetch
    for (int base = 32; base < deg; base += 8) {
      const int j = base + g;
      const bool val = j < deg;
      const unsigned int en = val ? csr2[s + j] : (unsigned int)wid;
      const unsigned src = (unsigned)upk_src(en, N);
      float hv[8];
      dec_fp8x8(*(const uint2*)(fhat + ((src << 6) | ((unsigned)sub << 3))), hv);
      float d = 0.f;
#pragma unroll
      for (int i = 0; i < 8; ++i) d += fn[i] * hv[i];
      d += __shfl_xor(d, 1, 64);
      d += __shfl_xor(d, 2, 64);
      d += __shfl_xor(d, 4, 64);
      float l = aln + a_r[src];
      l = (l >= 0.f) ? l : NEG_SLOPE * l;
      if (val) {
        m1 = fmaxf(m1, l);
        m2 = fmaxf(m2, d);
        if (sub == 0) lc[j] = make_float2(l, d);
      }
    }
    m1 = fmaxf(m1, __shfl_xor(m1, 8, 64));
    m1 = fmaxf(m1, __shfl_xor(m1, 16, 64));
    m1 = fmaxf(m1, __shfl_xor(m1, 32, 64));
    m2 = fmaxf(m2, __shfl_xor(m2, 8, 64));
    m2 = fmaxf(m2, __shfl_xor(m2, 16, 64));
    m2 = fmaxf(m2, __shfl_xor(m2, 32, 64));

    // ---- phase 2: dual softmax sums + fused p (deg <= 64 always) ----
    float el0 = 0.f, ec0 = 0.f, gg0 = 0.f;
    int q0 = 0;
    float ps1 = 0.f, ps2 = 0.f;
    if (lane < deg) {
      const unsigned int en = csr2[s + lane];  // coalesced, L2-hot
      q0 = upk_src(en, N);
      gg0 = upk_gate(en);
      float2 t = lc[lane];
      el0 = __expf(t.x - m1);
      ec0 = __expf(t.y - m2);
      ps1 = el0;
      ps2 = ec0;
    }
    const float rs1 = 1.f / (wred_sum(ps1) + EPS_SM);
    const float rs2 = 1.f / (wred_sum(ps2) + EPS_SM);

    float sp = 0.f;
    if (lane < deg) {
      float tt = (ob * el0 * rs1 + bb * ec0 * rs2) * gg0;
      float p0 = __expf(tt - 1.f);
      sp = p0;
      sg[lane] = make_float2(__int_as_float(q0), p0);  // (src, p)
    }
    const float rinv = 1.f / (wred_sum(sp) + EPS_SM);

    // ---- phase 3: register-resident Hmat for iters 0-3; gathers for tail ----
    float acc[8] = {0.f, 0.f, 0.f, 0.f, 0.f, 0.f, 0.f, 0.f};
#pragma unroll
    for (int kk = 0; kk < 4; ++kk) {
      const int base = kk * 8;
      if (base < deg) {
        const int j = base + g;
        const float pv = (j < deg) ? sg[j].y : 0.f;
        float hv[8];
        unp8(hm[kk], hv);
#pragma unroll
        for (int i = 0; i < 8; ++i) acc[i] += pv * hv[i];
      }
    }
    for (int base = 32; base < deg; base += 8) {
      const int j = base + g;
      float2 en = (j < deg) ? sg[j] : make_float2(__int_as_float(wid), 0.f);
      const float pv = en.y;
      const unsigned srcv = (unsigned)__float_as_int(en.x);
      float hv[8];
      unp8(*(const uint4*)(HmatB + ((srcv << 7) | ((unsigned)sub << 4))), hv);
#pragma unroll
      for (int i = 0; i < 8; ++i) acc[i] += pv * hv[i];
    }
#pragma unroll
    for (int i = 0; i < 8; ++i) {
      acc[i] += __shfl_xor(acc[i], 8, 64);
      acc[i] += __shfl_xor(acc[i], 16, 64);
      acc[i] += __shfl_xor(acc[i], 32, 64);
    }
    if (g == 0) {
#pragma unroll
      for (int i = 0; i < 8; ++i) lds_t[8 * sub + i] = acc[i];
    }
    v = lds_t[lane] * rinv + ldv(bias, lane, f32);
  } else {
    // ============ slow path: exact 3-pass over raw edge list ============
    // (deg > CAP; probability ~1e-10 on Poisson(25.6) data — correctness only)
    const int wide = flags[1];
    lds_t[lane] = 0.f;
    float m1 = -1e30f, m2 = -1e30f;
    for (int e64 = lane; e64 < E; e64 += 64) {
      int dd = wide ? ei[2 * (size_t)E + 2 * (size_t)e64] : ei[(size_t)E + e64];
      if (dd != wid) continue;
      int ss = wide ? ei[2 * (size_t)e64] : ei[e64];
      ss = min(max(ss, 0), N - 1);
      float l = aln + a_r[ss];
      l = (l >= 0.f) ? l : NEG_SLOPE * l;
      float c = slow_cos(fhat, wid, ss);
      m1 = fmaxf(m1, l);
      m2 = fmaxf(m2, c);
    }
    m1 = wred_max(m1);
    m2 = wred_max(m2);
    float ps1 = 0.f, ps2 = 0.f;
    for (int e64 = lane; e64 < E; e64 += 64) {
      int dd = wide ? ei[2 * (size_t)E + 2 * (size_t)e64] : ei[(size_t)E + e64];
      if (dd != wid) continue;
      int ss = wide ? ei[2 * (size_t)e64] : ei[e64];
      ss = min(max(ss, 0), N - 1);
      float l = aln + a_r[ss];
      l = (l >= 0.f) ? l : NEG_SLOPE * l;
      float c = slow_cos(fhat, wid, ss);
      ps1 += __expf(l - m1);
      ps2 += __expf(c - m2);
    }
    const float rs1 = 1.f / (wred_sum(ps1) + EPS_SM);
    const float rs2 = 1.f / (wred_sum(ps2) + EPS_SM);
    float sp = 0.f;
    for (int e64 = lane; e64 < E; e64 += 64) {
      int dd = wide ? ei[2 * (size_t)E + 2 * (size_t)e64] : ei[(size_t)E + e64];
      if (dd != wid) continue;
      int ss = wide ? ei[2 * (size_t)e64] : ei[e64];
      ss = min(max(ss, 0), N - 1);
      float l = aln + a_r[ss];
      l = (l >= 0.f) ? l : NEG_SLOPE * l;
      float c = slow_cos(fhat, wid, ss);
      float gx = gate_of(ldv(w, e64, f32));
      float px = __expf((ob * __expf(l - m1) * rs1 + bb * __expf(c - m2) * rs2) * gx - 1.f);
      sp += px;
      for (int q = 0; q < D; ++q)
        atomicAdd(&lds_t[q], px * __bfloat162float(Hmat[(size_t)ss * D + q]));
    }
    const float rinv = 1.f / (wred_sum(sp) + EPS_SM);
    v = lds_t[lane] * rinv + ldv(bias, lane, f32);
  }

  v = elu1(v);  // elu inside _cosgat
  if (mode == 1) {
    // fused residual MLP: relu(x@rW1+rb1)@rW2+rb2 — LDS-broadcast GEMMs
    float xv = ldv(x, (size_t)wid * D + lane, f32);
    float b0_ = ldv(rb1, lane, f32);
    __syncthreads();        // lds_t free for reuse (v already read)
    lds_t[lane] = xv;
    __syncthreads();
    float a2;
    float h0 = 0.f, h1 = 0.f, h2 = 0.f, h3 = 0.f;
    if (f32) {
      const float* w1 = (const float*)rW1;
      const float* w2 = (const float*)rW2;
#pragma unroll 4
      for (int k = 0; k < D; k += 4) {
        h0 += lds_t[k] * w1[k * D + lane];
        h1 += lds_t[k + 1] * w1[(k + 1) * D + lane];
        h2 += lds_t[k + 2] * w1[(k + 2) * D + lane];
        h3 += lds_t[k + 3] * w1[(k + 3) * D + lane];
      }
      float tr = fmaxf(b0_ + (h0 + h1) + (h2 + h3), 0.f);
      __syncthreads();
      lds_t[lane] = tr;
      __syncthreads();
      float g0 = 0.f, g1 = 0.f, g2 = 0.f, g3 = 0.f;
#pragma unroll 4
      for (int k = 0; k < D; k += 4) {
        g0 += lds_t[k] * w2[k * D + lane];
        g1 += lds_t[k + 1] * w2[(k + 1) * D + lane];
        g2 += lds_t[k + 2] * w2[(k + 2) * D + lane];
        g3 += lds_t[k + 3] * w2[(k + 3) * D + lane];
      }
      a2 = ((const float*)rb2)[lane] + (g0 + g1) + (g2 + g3);
    } else {
      const __hip_bfloat16* w1 = (const __hip_bfloat16*)rW1;
      const __hip_bfloat16* w2 = (const __hip_bfloat16*)rW2;
#pragma unroll 4
      for (int k = 0; k < D; k += 4) {
        h0 += lds_t[k] * __bfloat162float(w1[k * D + lane]);
        h1 += lds_t[k + 1] * __bfloat162float(w1[(k + 1) * D + lane]);
        h2 += lds_t[k + 2] * __bfloat162float(w1[(k + 2) * D + lane]);
        h3 += lds_t[k + 3] * __bfloat162float(w1[(k + 3) * D + lane]);
      }
      float tr = fmaxf(b0_ + (h0 + h1) + (h2 + h3), 0.f);
      __syncthreads();
      lds_t[lane] = tr;
      __syncthreads();
      float g0 = 0.f, g1 = 0.f, g2 = 0.f, g3 = 0.f;
#pragma unroll 4
      for (int k = 0; k < D; k += 4) {
        g0 += lds_t[k] * __bfloat162float(w2[k * D + lane]);
        g1 += lds_t[k + 1] * __bfloat162float(w2[(k + 1) * D + lane]);
        g2 += lds_t[k + 2] * __bfloat162float(w2[(k + 2) * D + lane]);
        g3 += lds_t[k + 3] * __bfloat162float(w2[(k + 3) * D + lane]);
      }
      a2 = __bfloat162float(((const __hip_bfloat16*)rb2)[lane]) + (g0 + g1) + (g2 + g3);
    }
    stv(out, (size_t)wid * D + lane, f32, sane(v + a2));
  } else {
    v = elu1(v);  // inter-layer elu
    if (mode == 0) {
      __syncthreads();  // lds_t free for reuse as prep staging
      prep_node(sane(v), f32, wid, lane, Wn, attn, fh2, Hm2, al2, ar2, lds_t);
    } else {
      stv(out, (size_t)wid * D + lane, f32, sane(v));
    }
  }
}

extern "C" void kernel_launch(void* const* d_in, const int* in_sizes, int n_in,
                              void* d_out, int out_size, void* d_ws, size_t ws_size,
                              hipStream_t stream) {
  const void* x = d_in[0];
  const int* ei = (const int*)d_in[1];
  const void* w = d_in[2];
  const void* W0 = d_in[3];
  const void* att0 = d_in[4];
  const void* beta0 = d_in[5];
  const void* b0 = d_in[6];
  const void* W1 = d_in[7];
  const void* att1 = d_in[8];
  const void* beta1 = d_in[9];
  const void* b1 = d_in[10];
  const void* rW1 = d_in[11];
  const void* rb1 = d_in[12];
  const void* rW2 = d_in[13];
  const void* rb2 = d_in[14];

  const int N = in_sizes[0] / D;
  const int E = in_sizes[2];

  char* base = (char*)d_ws;
  size_t off = 0;
  auto alloc = [&](size_t bytes) -> void* {
    void* p = base + off;
    off += (bytes + 255) & ~(size_t)255;
    return p;
  };
  // always-needed tier
  int* flags = (int*)alloc(256);
  int* cnt = (int*)alloc((size_t)N * 4);
  unsigned int* csr2 = (unsigned int*)alloc((size_t)N * CAP * 4);
  unsigned char* fhat = (unsigned char*)alloc((size_t)N * D);
  __hip_bfloat16* Hmat = (__hip_bfloat16*)alloc((size_t)N * D * 2);
  float* a_l = (float*)alloc((size_t)N * 4);
  float* a_r = (float*)alloc((size_t)N * 4);
  // fused tier (second-layer prep buffers)
  unsigned char* fhat2 = (unsigned char*)alloc((size_t)N * D);
  __hip_bfloat16* Hmat2 = (__hip_bfloat16*)alloc((size_t)N * D * 2);
  float* a_l2 = (float*)alloc((size_t)N * 4);
  float* a_r2 = (float*)alloc((size_t)N * 4);
  const bool fused = (off <= ws_size);

  hipMemsetAsync(cnt, 0, (size_t)N * 4, stream);
  k_all<<<N, 64, 0, stream>>>((const unsigned short*)x, ei, w, flags, cnt,
                              x, W0, att0, fhat, Hmat, a_l, a_r, csr2, N, E);

  if (fused) {
    k_edge<<<N, 64, 0, stream>>>(cnt, csr2, ei, w, fhat, Hmat, a_l, a_r,
                                 beta0, b0, x, rW1, rb1, rW2, rb2,
                                 W1, att1, fhat2, Hmat2, a_l2, a_r2,
                                 flags, d_out, N, E, 0);
    k_edge<<<N, 64, 0, stream>>>(cnt, csr2, ei, w, fhat2, Hmat2, a_l2, a_r2,
                                 beta1, b1, x, rW1, rb1, rW2, rb2,
                                 nullptr, nullptr, nullptr, nullptr, nullptr, nullptr,
                                 flags, d_out, N, E, 1);
  } else {
    k_edge<<<N, 64, 0, stream>>>(cnt, csr2, ei, w, fhat, Hmat, a_l, a_r,
                                 beta0, b0, x, rW1, rb1, rW2, rb2,
                                 nullptr, nullptr, nullptr, nullptr, nullptr, nullptr,
                                 flags, d_out, N, E, 2);
    k_prep<<<N, 64, 0, stream>>>(d_out, W1, att1, flags, fhat, Hmat, a_l, a_r, N);
    k_edge<<<N, 64, 0, stream>>>(cnt, csr2, ei, w, fhat, Hmat, a_l, a_r,
                                 beta1, b1, x, rW1, rb1, rW2, rb2,
                                 nullptr, nullptr, nullptr, nullptr, nullptr, nullptr,
                                 flags, d_out, N, E, 1);
  }
}